// Round 12
// baseline (949.207 us; speedup 1.0000x reference)
//
#include <hip/hip_runtime.h>
#include <hip/hip_bf16.h>

#define N_FINE 50000
#define N_COARSE 2000
#define N_EDGES 300000

typedef short  s16x8 __attribute__((ext_vector_type(8)));
typedef float  f32x4 __attribute__((ext_vector_type(4)));

static inline int cdiv(int a, int b) { return (a + b - 1) / b; }

__device__ __forceinline__ short f2b(float f) {      // f32 -> bf16 RNE
    unsigned u = __builtin_bit_cast(unsigned, f);
    unsigned r = (u + 0x7fffu + ((u >> 16) & 1u)) >> 16;
    return (short)r;
}
__device__ __forceinline__ float b2f(short s) {
    return __builtin_bit_cast(float, ((unsigned)(unsigned short)s) << 16);
}

// ---------------- CSR build ----------------

__global__ void count_edges_kernel(const int* __restrict__ col, int* __restrict__ counts, int ne) {
    int e = blockIdx.x * 256 + threadIdx.x;
    if (e < ne) atomicAdd(&counts[col[e]], 1);
}

__global__ void compute_dis_kernel(const int* __restrict__ counts, float* __restrict__ dis, int n) {
    int i = blockIdx.x * 256 + threadIdx.x;
    if (i < n) dis[i] = rsqrtf((float)(counts[i] + 1));   // +1 self loop
}

// two-level scan: per-block 1024-wide exclusive scan + block totals
__global__ __launch_bounds__(1024) void scan_block_kernel(const int* __restrict__ counts,
        int* __restrict__ rowptr, int* __restrict__ blksum, int n) {
    __shared__ int wsum[16];
    int tid = threadIdx.x, lane = tid & 63, wv = tid >> 6;
    int i = blockIdx.x * 1024 + tid;
    int v = (i < n) ? counts[i] : 0;
    int x = v;
#pragma unroll
    for (int off = 1; off < 64; off <<= 1) {
        int t = __shfl_up(x, off);
        if (lane >= off) x += t;
    }
    if (lane == 63) wsum[wv] = x;
    __syncthreads();
    if (wv == 0) {
        int s = (lane < 16) ? wsum[lane] : 0;
#pragma unroll
        for (int off = 1; off < 16; off <<= 1) {
            int t = __shfl_up(s, off);
            if (lane >= off) s += t;
        }
        if (lane < 16) wsum[lane] = s;
    }
    __syncthreads();
    int prefix = (wv > 0) ? wsum[wv - 1] : 0;
    int incl = prefix + x;
    if (i < n) rowptr[i] = incl - v;   // exclusive
    if (tid == 1023) blksum[blockIdx.x] = incl;
}

__global__ void scan_tops_kernel(int* __restrict__ blksum, int nb) {
    int lane = threadIdx.x;
    int v = (lane < nb) ? blksum[lane] : 0;
    int x = v;
#pragma unroll
    for (int off = 1; off < 64; off <<= 1) {
        int t = __shfl_up(x, off);
        if (lane >= off) x += t;
    }
    if (lane < nb) blksum[lane] = x - v;
}

__global__ void scan_add_kernel(int* __restrict__ rowptr, const int* __restrict__ blksum, int n) {
    int i = blockIdx.x * 256 + threadIdx.x;
    if (i < n) rowptr[i] += blksum[i >> 10];
    else if (i == n) rowptr[n] = N_EDGES;
}

__global__ void scatter_edges_kernel(const int* __restrict__ row, const int* __restrict__ col,
                                     int* __restrict__ cursor, int* __restrict__ esrc, int ne) {
    int e = blockIdx.x * 256 + threadIdx.x;
    if (e < ne) {
        int p = atomicAdd(&cursor[col[e]], 1);
        esrc[p] = row[e];
    }
}

// ---------------- weight prep: WT[n][k] = bf16(W[k][n]), 512x512, LDS-tiled ----------------

__global__ __launch_bounds__(256) void wt4_kernel(
        const float* __restrict__ W0, const float* __restrict__ W1,
        const float* __restrict__ W2, const float* __restrict__ W3,
        short* __restrict__ T0, short* __restrict__ T1,
        short* __restrict__ T2, short* __restrict__ T3) {
    __shared__ float tile[32][33];
    const float* W; short* WT;
    switch (blockIdx.y) {
        case 0: W = W0; WT = T0; break;
        case 1: W = W1; WT = T1; break;
        case 2: W = W2; WT = T2; break;
        default: W = W3; WT = T3; break;
    }
    int bx = blockIdx.x & 15;        // k-tile
    int by = blockIdx.x >> 4;        // n-tile
    int tx = threadIdx.x & 31;
    int ty = threadIdx.x >> 5;
#pragma unroll
    for (int i = 0; i < 4; ++i) {
        int k = bx * 32 + ty + i * 8;
        int n = by * 32 + tx;
        tile[ty + i * 8][tx] = W[(size_t)k * 512 + n];   // coalesced load
    }
    __syncthreads();
#pragma unroll
    for (int i = 0; i < 4; ++i) {
        int n = by * 32 + ty + i * 8;
        int k = bx * 32 + tx;
        WT[(size_t)n * 512 + k] = f2b(tile[tx][ty + i * 8]);  // coalesced store
    }
}

// ---------------- layer kernels ----------------

// first layer: [M,6] @ [6,512], scaled by dis, bf16 out; 8 outputs/thread
__global__ void pre0_kernel(const float* __restrict__ x, const float* __restrict__ sdf,
                            const float* __restrict__ W, const float* __restrict__ dis,
                            short* __restrict__ B, int M) {
    int idx = blockIdx.x * 256 + threadIdx.x;
    int m = idx >> 6, n8 = (idx & 63) << 3;
    if (m >= M) return;
    float a0 = x[m*5+0], a1 = x[m*5+1], a2 = x[m*5+2], a3 = x[m*5+3], a4 = x[m*5+4], a5 = sdf[m];
    float d = dis[m];
    s16x8 o;
#pragma unroll
    for (int j = 0; j < 8; ++j) {
        int n = n8 + j;
        float t = a0*W[n] + a1*W[512+n] + a2*W[1024+n] + a3*W[1536+n] + a4*W[2048+n] + a5*W[2560+n];
        o[j] = f2b(d * t);
    }
    *(s16x8*)&B[(size_t)m*512 + n8] = o;
}

// MFMA GEMM v7 -- NO-LDS direct-to-register streaming.
// 256 thr / 4 waves (2x2), 128x128 block tile, wave owns 64x64, acc[4][4].
// Each wave loads its MFMA fragments straight from global (per-lane dwordx4;
// one instr = 16 rows x 64B -> 16x 64B L2 requests). Reuse is served by L2
// (A shared by 4 col-panels on the same XCD; WT 0.5 MB L2-hot). No barriers,
// no LDS, no in-order GL16 retirement queue -- misses complete out of order
// and waves stream independently. Manual 1-step register prefetch.
__global__ __launch_bounds__(256) void gemm512_mfma_kernel(
        const short* __restrict__ A, const short* __restrict__ WT,
        const float* __restrict__ dis, short* __restrict__ C, int M,
        const float* __restrict__ A2, const float* __restrict__ W2) {
    int tid  = threadIdx.x;
    int lane = tid & 63;
    int w    = tid >> 6;          // 0..3
    int wm   = w >> 1, wn = w & 1;

    int nrp = (M + 127) >> 7;     // 391 row-panels
    int id = blockIdx.x;
    int rp = (id >> 5) * 8 + (id & 7);   // id&7 fixed per rp-group -> same XCD
    int cp = (id >> 3) & 3;              // col-panel 0..3
    if (rp >= nrp) return;
    int row0 = rp * 128;
    int col0 = cp * 128;

    int r16 = lane & 15;          // row within fragment
    int kc  = lane >> 4;          // 16B chunk 0..3 within a 64B k-slab

    // fragment base pointers (advance by 32 shorts per K-step)
    const short* pA[4];
    const short* pB[4];
#pragma unroll
    for (int mi = 0; mi < 4; ++mi) {
        int ar = row0 + wm * 64 + mi * 16 + r16; if (ar >= M) ar = M - 1;
        pA[mi] = A + (size_t)ar * 512 + kc * 8;
    }
#pragma unroll
    for (int ni = 0; ni < 4; ++ni) {
        int br = col0 + wn * 64 + ni * 16 + r16;
        pB[ni] = WT + (size_t)br * 512 + kc * 8;
    }

    f32x4 acc[4][4] = {};
    s16x8 a0, a1, a2, a3, b0, b1, b2, b3;
    s16x8 na0, na1, na2, na3, nb0, nb1, nb2, nb3;

    a0 = *(const s16x8*)pA[0]; a1 = *(const s16x8*)pA[1];
    a2 = *(const s16x8*)pA[2]; a3 = *(const s16x8*)pA[3];
    b0 = *(const s16x8*)pB[0]; b1 = *(const s16x8*)pB[1];
    b2 = *(const s16x8*)pB[2]; b3 = *(const s16x8*)pB[3];

#pragma unroll 1
    for (int t = 0; t < 16; ++t) {
        if (t < 15) {
            int ko = (t + 1) * 32;
            na0 = *(const s16x8*)(pA[0] + ko); na1 = *(const s16x8*)(pA[1] + ko);
            na2 = *(const s16x8*)(pA[2] + ko); na3 = *(const s16x8*)(pA[3] + ko);
            nb0 = *(const s16x8*)(pB[0] + ko); nb1 = *(const s16x8*)(pB[1] + ko);
            nb2 = *(const s16x8*)(pB[2] + ko); nb3 = *(const s16x8*)(pB[3] + ko);
        }
        acc[0][0] = __builtin_amdgcn_mfma_f32_16x16x32_bf16(a0, b0, acc[0][0], 0, 0, 0);
        acc[0][1] = __builtin_amdgcn_mfma_f32_16x16x32_bf16(a0, b1, acc[0][1], 0, 0, 0);
        acc[0][2] = __builtin_amdgcn_mfma_f32_16x16x32_bf16(a0, b2, acc[0][2], 0, 0, 0);
        acc[0][3] = __builtin_amdgcn_mfma_f32_16x16x32_bf16(a0, b3, acc[0][3], 0, 0, 0);
        acc[1][0] = __builtin_amdgcn_mfma_f32_16x16x32_bf16(a1, b0, acc[1][0], 0, 0, 0);
        acc[1][1] = __builtin_amdgcn_mfma_f32_16x16x32_bf16(a1, b1, acc[1][1], 0, 0, 0);
        acc[1][2] = __builtin_amdgcn_mfma_f32_16x16x32_bf16(a1, b2, acc[1][2], 0, 0, 0);
        acc[1][3] = __builtin_amdgcn_mfma_f32_16x16x32_bf16(a1, b3, acc[1][3], 0, 0, 0);
        acc[2][0] = __builtin_amdgcn_mfma_f32_16x16x32_bf16(a2, b0, acc[2][0], 0, 0, 0);
        acc[2][1] = __builtin_amdgcn_mfma_f32_16x16x32_bf16(a2, b1, acc[2][1], 0, 0, 0);
        acc[2][2] = __builtin_amdgcn_mfma_f32_16x16x32_bf16(a2, b2, acc[2][2], 0, 0, 0);
        acc[2][3] = __builtin_amdgcn_mfma_f32_16x16x32_bf16(a2, b3, acc[2][3], 0, 0, 0);
        acc[3][0] = __builtin_amdgcn_mfma_f32_16x16x32_bf16(a3, b0, acc[3][0], 0, 0, 0);
        acc[3][1] = __builtin_amdgcn_mfma_f32_16x16x32_bf16(a3, b1, acc[3][1], 0, 0, 0);
        acc[3][2] = __builtin_amdgcn_mfma_f32_16x16x32_bf16(a3, b2, acc[3][2], 0, 0, 0);
        acc[3][3] = __builtin_amdgcn_mfma_f32_16x16x32_bf16(a3, b3, acc[3][3], 0, 0, 0);
        if (t < 15) {
            a0 = na0; a1 = na1; a2 = na2; a3 = na3;
            b0 = nb0; b1 = nb1; b2 = nb2; b3 = nb3;
        }
    }

    int rbase = row0 + wm * 64;
    int cbase = col0 + wn * 64;
#pragma unroll
    for (int mi = 0; mi < 4; ++mi) {
#pragma unroll
        for (int r = 0; r < 4; ++r) {
            int row = rbase + mi * 16 + (lane >> 4) * 4 + r;
            if (row >= M) continue;
            float d = dis[row];
            float a20 = 0.f, a21 = 0.f, a22 = 0.f;
            if (A2) { a20 = A2[row*3+0]; a21 = A2[row*3+1]; a22 = A2[row*3+2]; }
#pragma unroll
            for (int ni = 0; ni < 4; ++ni) {
                int col = cbase + ni * 16 + (lane & 15);
                float v = acc[mi][ni][r];
                if (A2) v += a20 * W2[col] + a21 * W2[512 + col] + a22 * W2[1024 + col];
                C[(size_t)row * 512 + col] = f2b(d * v);
            }
        }
    }
}

// out[i,:] = bf16(relu( dis[i]*(sum_nbr B[src,:] + B[i,:]) + bias ))
// one wave/node; 4-edge windowed gather for memory-level parallelism
__global__ __launch_bounds__(256) void spmm512_kernel(
        const short* __restrict__ B, const int* __restrict__ rowptr, const int* __restrict__ esrc,
        const float* __restrict__ dis, const float* __restrict__ bias,
        short* __restrict__ out, int M) {
    int node = blockIdx.x * 4 + (threadIdx.x >> 6);
    int lane = threadIdx.x & 63;
    if (node >= M) return;
    const s16x8* Bv = (const s16x8*)B;
    s16x8 v = Bv[(size_t)node * 64 + lane];   // self loop
    float acc[8];
#pragma unroll
    for (int j = 0; j < 8; ++j) acc[j] = b2f(v[j]);
    int s = rowptr[node], e = rowptr[node + 1];
    int p = s;
    for (; p + 4 <= e; p += 4) {
        int s0 = esrc[p], s1 = esrc[p+1], s2 = esrc[p+2], s3 = esrc[p+3];
        s16x8 t0 = Bv[(size_t)s0 * 64 + lane];
        s16x8 t1 = Bv[(size_t)s1 * 64 + lane];
        s16x8 t2 = Bv[(size_t)s2 * 64 + lane];
        s16x8 t3 = Bv[(size_t)s3 * 64 + lane];
#pragma unroll
        for (int j = 0; j < 8; ++j)
            acc[j] += (b2f(t0[j]) + b2f(t1[j])) + (b2f(t2[j]) + b2f(t3[j]));
    }
    for (; p < e; ++p) {
        int src = esrc[p];
        s16x8 t = Bv[(size_t)src * 64 + lane];
#pragma unroll
        for (int j = 0; j < 8; ++j) acc[j] += b2f(t[j]);
    }
    float d = dis[node];
    const float4* bp = (const float4*)bias;
    float4 bb0 = bp[lane * 2], bb1 = bp[lane * 2 + 1];
    float r[8];
    r[0] = d*acc[0] + bb0.x; r[1] = d*acc[1] + bb0.y; r[2] = d*acc[2] + bb0.z; r[3] = d*acc[3] + bb0.w;
    r[4] = d*acc[4] + bb1.x; r[5] = d*acc[5] + bb1.y; r[6] = d*acc[6] + bb1.z; r[7] = d*acc[7] + bb1.w;
    s16x8 o;
#pragma unroll
    for (int j = 0; j < 8; ++j) o[j] = f2b(fmaxf(r[j], 0.f));
    ((s16x8*)out)[(size_t)node * 64 + lane] = o;
}

// final GEMM: B3[M,3] = dis .* (A_bf16[M,512] @ W[512,3]); one wave per row
__global__ __launch_bounds__(256) void gemm_n3_kernel(
        const short* __restrict__ A, const float* __restrict__ W,
        const float* __restrict__ dis, float* __restrict__ B3, int M) {
    int wid = (blockIdx.x * 256 + threadIdx.x) >> 6;
    int lane = threadIdx.x & 63;
    if (wid >= M) return;
    s16x8 v = ((const s16x8*)A)[(size_t)wid * 64 + lane];
    float s0 = 0.f, s1 = 0.f, s2 = 0.f;
#pragma unroll
    for (int j = 0; j < 8; ++j) {
        float a = b2f(v[j]);
        int k = lane * 8 + j;
        s0 += a * W[k*3+0];
        s1 += a * W[k*3+1];
        s2 += a * W[k*3+2];
    }
    for (int off = 32; off > 0; off >>= 1) {
        s0 += __shfl_down(s0, off);
        s1 += __shfl_down(s1, off);
        s2 += __shfl_down(s2, off);
    }
    if (lane == 0) {
        float d = dis[wid];
        B3[wid*3+0] = d * s0;
        B3[wid*3+1] = d * s1;
        B3[wid*3+2] = d * s2;
    }
}

__global__ void spmm3_kernel(const float* __restrict__ B3, const int* __restrict__ rowptr,
                             const int* __restrict__ esrc, const float* __restrict__ dis,
                             const float* __restrict__ bias, float* __restrict__ out, int M) {
    int i = blockIdx.x * 256 + threadIdx.x;
    if (i >= M) return;
    float a0 = B3[i*3+0], a1 = B3[i*3+1], a2 = B3[i*3+2];
    int s = rowptr[i], e = rowptr[i + 1];
    for (int p = s; p < e; ++p) {
        int src = esrc[p];
        a0 += B3[src*3+0];
        a1 += B3[src*3+1];
        a2 += B3[src*3+2];
    }
    float d = dis[i];
    out[i*3+0] = d * a0 + bias[0];
    out[i*3+1] = d * a1 + bias[1];
    out[i*3+2] = d * a2 + bias[2];
}

// KNN interpolate: block = 64 fine nodes x 4 waves; wave w scans coarse chunk of 500.
__global__ __launch_bounds__(256) void knn_kernel(
        const float* __restrict__ x, const float* __restrict__ cpos,
        const float* __restrict__ cy, float* __restrict__ fy, int M) {
    __shared__ float sd[12][64];
    __shared__ int   si[12][64];
    int lane = threadIdx.x & 63;
    int w = threadIdx.x >> 6;
    int gi = blockIdx.x * 64 + lane;
    int i = (gi < M) ? gi : (M - 1);
    float px = x[i*5+0], py = x[i*5+1];
    float pn2 = px*px + py*py;
    float d0 = 3.0e38f, d1 = 3.0e38f, d2 = 3.0e38f;
    int i0 = 0x7fffffff, i1 = 0x7fffffff, i2 = 0x7fffffff;
    int c0 = w * (N_COARSE / 4), c1 = c0 + (N_COARSE / 4);
    for (int c = c0; c < c1; ++c) {
        float a = cpos[c*2+0], b = cpos[c*2+1];
        float sn2 = a*a + b*b;                       // ref formula
        float d = pn2 + sn2 - 2.f * (px * a + py * b);
        if (d < d2) {
            if (d < d1) {
                d2 = d1; i2 = i1;
                if (d < d0) { d1 = d0; i1 = i0; d0 = d; i0 = c; }
                else       { d1 = d;  i1 = c; }
            } else { d2 = d; i2 = c; }
        }
    }
    sd[w*3+0][lane] = d0; si[w*3+0][lane] = i0;
    sd[w*3+1][lane] = d1; si[w*3+1][lane] = i1;
    sd[w*3+2][lane] = d2; si[w*3+2][lane] = i2;
    __syncthreads();
    if (w != 0 || gi >= M) return;
    float cd[12]; int ci[12];
#pragma unroll
    for (int q = 0; q < 12; ++q) { cd[q] = sd[q][lane]; ci[q] = si[q][lane]; }
    float bd[3]; int bi[3];
#pragma unroll
    for (int s = 0; s < 3; ++s) {
        float best = 3.4e38f; int besti = 0x7fffffff; int bq = 0;
#pragma unroll
        for (int q = 0; q < 12; ++q) {
            bool better = (cd[q] < best) || (cd[q] == best && ci[q] < besti);
            if (better) { best = cd[q]; besti = ci[q]; bq = q; }
        }
        bd[s] = best; bi[s] = besti;
        cd[bq] = 3.4e38f; ci[bq] = 0x7fffffff;
    }
    float w0 = 1.f / fmaxf(bd[0], 1e-16f);
    float w1 = 1.f / fmaxf(bd[1], 1e-16f);
    float w2 = 1.f / fmaxf(bd[2], 1e-16f);
    float ws = w0 + w1 + w2;
    int j0 = bi[0], j1 = bi[1], j2 = bi[2];
#pragma unroll
    for (int j = 0; j < 3; ++j) {
        float v = w0 * cy[j0*3+j] + w1 * cy[j1*3+j] + w2 * cy[j2*3+j];
        fy[gi*3+j] = v / ws;
    }
}

// ---------------- launch ----------------

extern "C" void kernel_launch(void* const* d_in, const int* in_sizes, int n_in,
                              void* d_out, int out_size, void* d_ws, size_t ws_size,
                              hipStream_t stream) {
    const float* x        = (const float*)d_in[0];
    const float* sdf      = (const float*)d_in[1];
    const float* coarse_x = (const float*)d_in[2];
    const float* coarse_y = (const float*)d_in[3];
    const int*   eidx     = (const int*)d_in[4];
    const float* pre_W0   = (const float*)d_in[5];
    const float* pre_b0   = (const float*)d_in[6];
    const float* pre_W1   = (const float*)d_in[7];
    const float* pre_b1   = (const float*)d_in[8];
    const float* pre_W2   = (const float*)d_in[9];
    const float* pre_b2   = (const float*)d_in[10];
    const float* end_W0   = (const float*)d_in[11];
    const float* end_b0   = (const float*)d_in[12];
    const float* end_W1   = (const float*)d_in[13];
    const float* end_b1   = (const float*)d_in[14];
    const float* end_W2   = (const float*)d_in[15];
    const float* end_b2   = (const float*)d_in[16];
    float* out = (float*)d_out;

    const int M = N_FINE, NE = N_EDGES;
    const int* erow = eidx;
    const int* ecol = eidx + NE;

    char* base = (char*)d_ws;
    size_t off = 0;
    auto alloc = [&](size_t bytes) { char* p = base + off; off = (off + bytes + 255) & ~(size_t)255; return p; };
    int*   counts = (int*)  alloc((size_t)M * 4);
    int*   rowptr = (int*)  alloc((size_t)(M + 1) * 4);
    int*   cursor = (int*)  alloc((size_t)M * 4);
    int*   esrc   = (int*)  alloc((size_t)NE * 4);
    int*   blksum = (int*)  alloc((size_t)64 * 4);
    float* dis    = (float*)alloc((size_t)M * 4);
    float* fy     = (float*)alloc((size_t)M * 3 * 4);
    float* B3     = (float*)alloc((size_t)M * 3 * 4);
    short* WT1    = (short*)alloc((size_t)512 * 512 * 2);
    short* WT2    = (short*)alloc((size_t)512 * 512 * 2);
    short* WT3    = (short*)alloc((size_t)512 * 512 * 2);
    short* WT4    = (short*)alloc((size_t)512 * 512 * 2);
    short* bufA   = (short*)alloc((size_t)M * 512 * 2);
    short* bufB   = (short*)alloc((size_t)M * 512 * 2);
    (void)ws_size;

    // weight prep (one launch, 4 matrices)
    wt4_kernel<<<dim3(256, 4), 256, 0, stream>>>(pre_W1, pre_W2, end_W0 + 3 * 512, end_W1,
                                                 WT1, WT2, WT3, WT4);

    // CSR + degrees
    hipMemsetAsync(counts, 0, (size_t)M * 4, stream);
    count_edges_kernel<<<cdiv(NE, 256), 256, 0, stream>>>(ecol, counts, NE);
    compute_dis_kernel<<<cdiv(M, 256), 256, 0, stream>>>(counts, dis, M);
    int nb = cdiv(M, 1024);
    scan_block_kernel<<<nb, 1024, 0, stream>>>(counts, rowptr, blksum, M);
    scan_tops_kernel<<<1, 64, 0, stream>>>(blksum, nb);
    scan_add_kernel<<<cdiv(M + 1, 256), 256, 0, stream>>>(rowptr, blksum, M);
    hipMemcpyAsync(cursor, rowptr, (size_t)M * 4, hipMemcpyDeviceToDevice, stream);
    scatter_edges_kernel<<<cdiv(NE, 256), 256, 0, stream>>>(erow, ecol, cursor, esrc, NE);

    // KNN interpolate
    knn_kernel<<<cdiv(M, 64), 256, 0, stream>>>(x, coarse_x, coarse_y, fy, M);

    // gemm grid: 391 row-panels x 4 col-panels; id = (rp>>3)*32 + cp*8 + (rp&7)
    int nrp = cdiv(M, 128);
    int ggrid = cdiv(nrp, 8) * 32;
    int sgrid = cdiv(M, 4);

    pre0_kernel<<<cdiv(M * 64, 256), 256, 0, stream>>>(x, sdf, pre_W0, dis, bufB, M);
    spmm512_kernel<<<sgrid, 256, 0, stream>>>(bufB, rowptr, esrc, dis, pre_b0, bufA, M);

    gemm512_mfma_kernel<<<ggrid, 256, 0, stream>>>(bufA, WT1, dis, bufB, M, nullptr, nullptr);
    spmm512_kernel<<<sgrid, 256, 0, stream>>>(bufB, rowptr, esrc, dis, pre_b1, bufA, M);

    gemm512_mfma_kernel<<<ggrid, 256, 0, stream>>>(bufA, WT2, dis, bufB, M, nullptr, nullptr);
    spmm512_kernel<<<sgrid, 256, 0, stream>>>(bufB, rowptr, esrc, dis, pre_b2, bufA, M);

    gemm512_mfma_kernel<<<ggrid, 256, 0, stream>>>(bufA, WT3, dis, bufB, M, fy, end_W0);
    spmm512_kernel<<<sgrid, 256, 0, stream>>>(bufB, rowptr, esrc, dis, end_b0, bufA, M);

    gemm512_mfma_kernel<<<ggrid, 256, 0, stream>>>(bufA, WT4, dis, bufB, M, nullptr, nullptr);
    spmm512_kernel<<<sgrid, 256, 0, stream>>>(bufB, rowptr, esrc, dis, end_b1, bufA, M);

    gemm_n3_kernel<<<cdiv(M * 64, 256), 256, 0, stream>>>(bufA, end_W2, dis, B3, M);
    spmm3_kernel<<<cdiv(M, 256), 256, 0, stream>>>(B3, rowptr, esrc, dis, end_b2, out, M);
}

// Round 13
// 724.045 us; speedup vs baseline: 1.3110x; 1.3110x over previous
//
#include <hip/hip_runtime.h>
#include <hip/hip_bf16.h>

#define N_FINE 50000
#define N_COARSE 2000
#define N_EDGES 300000

typedef short  s16x8 __attribute__((ext_vector_type(8)));
typedef float  f32x4 __attribute__((ext_vector_type(4)));

static inline int cdiv(int a, int b) { return (a + b - 1) / b; }

__device__ __forceinline__ short f2b(float f) {      // f32 -> bf16 RNE
    unsigned u = __builtin_bit_cast(unsigned, f);
    unsigned r = (u + 0x7fffu + ((u >> 16) & 1u)) >> 16;
    return (short)r;
}
__device__ __forceinline__ float b2f(short s) {
    return __builtin_bit_cast(float, ((unsigned)(unsigned short)s) << 16);
}

#define GL16(gsrc, ldst) __builtin_amdgcn_global_load_lds( \
    (const __attribute__((address_space(1))) unsigned*)(gsrc), \
    (__attribute__((address_space(3))) unsigned*)(ldst), 16, 0, 0)

// ---------------- CSR build ----------------

__global__ void count_edges_kernel(const int* __restrict__ col, int* __restrict__ counts, int ne) {
    int e = blockIdx.x * 256 + threadIdx.x;
    if (e < ne) atomicAdd(&counts[col[e]], 1);
}

__global__ void compute_dis_kernel(const int* __restrict__ counts, float* __restrict__ dis, int n) {
    int i = blockIdx.x * 256 + threadIdx.x;
    if (i < n) dis[i] = rsqrtf((float)(counts[i] + 1));   // +1 self loop
}

// two-level scan: per-block 1024-wide exclusive scan + block totals
__global__ __launch_bounds__(1024) void scan_block_kernel(const int* __restrict__ counts,
        int* __restrict__ rowptr, int* __restrict__ blksum, int n) {
    __shared__ int wsum[16];
    int tid = threadIdx.x, lane = tid & 63, wv = tid >> 6;
    int i = blockIdx.x * 1024 + tid;
    int v = (i < n) ? counts[i] : 0;
    int x = v;
#pragma unroll
    for (int off = 1; off < 64; off <<= 1) {
        int t = __shfl_up(x, off);
        if (lane >= off) x += t;
    }
    if (lane == 63) wsum[wv] = x;
    __syncthreads();
    if (wv == 0) {
        int s = (lane < 16) ? wsum[lane] : 0;
#pragma unroll
        for (int off = 1; off < 16; off <<= 1) {
            int t = __shfl_up(s, off);
            if (lane >= off) s += t;
        }
        if (lane < 16) wsum[lane] = s;
    }
    __syncthreads();
    int prefix = (wv > 0) ? wsum[wv - 1] : 0;
    int incl = prefix + x;
    if (i < n) rowptr[i] = incl - v;   // exclusive
    if (tid == 1023) blksum[blockIdx.x] = incl;
}

__global__ void scan_tops_kernel(int* __restrict__ blksum, int nb) {
    int lane = threadIdx.x;
    int v = (lane < nb) ? blksum[lane] : 0;
    int x = v;
#pragma unroll
    for (int off = 1; off < 64; off <<= 1) {
        int t = __shfl_up(x, off);
        if (lane >= off) x += t;
    }
    if (lane < nb) blksum[lane] = x - v;
}

__global__ void scan_add_kernel(int* __restrict__ rowptr, const int* __restrict__ blksum, int n) {
    int i = blockIdx.x * 256 + threadIdx.x;
    if (i < n) rowptr[i] += blksum[i >> 10];
    else if (i == n) rowptr[n] = N_EDGES;
}

__global__ void scatter_edges_kernel(const int* __restrict__ row, const int* __restrict__ col,
                                     int* __restrict__ cursor, int* __restrict__ esrc, int ne) {
    int e = blockIdx.x * 256 + threadIdx.x;
    if (e < ne) {
        int p = atomicAdd(&cursor[col[e]], 1);
        esrc[p] = row[e];
    }
}

// ---------------- weight prep: WT[n][k] = bf16(W[k][n]), 512x512, LDS-tiled ----------------

__global__ __launch_bounds__(256) void wt4_kernel(
        const float* __restrict__ W0, const float* __restrict__ W1,
        const float* __restrict__ W2, const float* __restrict__ W3,
        short* __restrict__ T0, short* __restrict__ T1,
        short* __restrict__ T2, short* __restrict__ T3) {
    __shared__ float tile[32][33];
    const float* W; short* WT;
    switch (blockIdx.y) {
        case 0: W = W0; WT = T0; break;
        case 1: W = W1; WT = T1; break;
        case 2: W = W2; WT = T2; break;
        default: W = W3; WT = T3; break;
    }
    int bx = blockIdx.x & 15;        // k-tile
    int by = blockIdx.x >> 4;        // n-tile
    int tx = threadIdx.x & 31;
    int ty = threadIdx.x >> 5;
#pragma unroll
    for (int i = 0; i < 4; ++i) {
        int k = bx * 32 + ty + i * 8;
        int n = by * 32 + tx;
        tile[ty + i * 8][tx] = W[(size_t)k * 512 + n];   // coalesced load
    }
    __syncthreads();
#pragma unroll
    for (int i = 0; i < 4; ++i) {
        int n = by * 32 + ty + i * 8;
        int k = bx * 32 + tx;
        WT[(size_t)n * 512 + k] = f2b(tile[tx][ty + i * 8]);  // coalesced store
    }
}

// ---------------- layer kernels ----------------

// first layer: [M,6] @ [6,512], scaled by dis, bf16 out; 8 outputs/thread
__global__ void pre0_kernel(const float* __restrict__ x, const float* __restrict__ sdf,
                            const float* __restrict__ W, const float* __restrict__ dis,
                            short* __restrict__ B, int M) {
    int idx = blockIdx.x * 256 + threadIdx.x;
    int m = idx >> 6, n8 = (idx & 63) << 3;
    if (m >= M) return;
    float a0 = x[m*5+0], a1 = x[m*5+1], a2 = x[m*5+2], a3 = x[m*5+3], a4 = x[m*5+4], a5 = sdf[m];
    float d = dis[m];
    s16x8 o;
#pragma unroll
    for (int j = 0; j < 8; ++j) {
        int n = n8 + j;
        float t = a0*W[n] + a1*W[512+n] + a2*W[1024+n] + a3*W[1536+n] + a4*W[2048+n] + a5*W[2560+n];
        o[j] = f2b(d * t);
    }
    *(s16x8*)&B[(size_t)m*512 + n8] = o;
}

// MFMA GEMM v8: BM=256 x BN=128, BK=64 (128B segments), depth-2 counted-vmcnt
// (r9's exact proven schedule), A+B 3-buffered (LDS 144 KB, 1 block/CU,
// 8 waves). 512 thr / 8 waves (4Mx2N), per-wave 64x64, acc[4][4] (r10 epilogue
// geometry). Staged volume 301 MB (vs r10's 400, r9's 800) at the proven
// ~8 TB/s 128B-segment operating point. Chunk-XOR swizzle both sides.
// XCD map: 4 col-panels of one row-panel share id%8 -> same XCD L2.
__global__ __launch_bounds__(512) void gemm512_mfma_kernel(
        const short* __restrict__ A, const short* __restrict__ WT,
        const float* __restrict__ dis, short* __restrict__ C, int M,
        const float* __restrict__ A2, const float* __restrict__ W2) {
    __shared__ __attribute__((aligned(16))) short As[3 * 256 * 64];   // 96 KB
    __shared__ __attribute__((aligned(16))) short Bs[3 * 128 * 64];   // 48 KB
    int tid  = threadIdx.x;
    int lane = tid & 63;
    int w    = tid >> 6;          // 0..7
    int wm   = w >> 1, wn = w & 1;

    int nrp = (M + 255) >> 8;     // 196 row-panels
    int id = blockIdx.x;
    int rp = (id >> 5) * 8 + (id & 7);   // id&7 fixed per rp-group -> same XCD
    int cp = (id >> 3) & 3;              // col-panel 0..3
    if (rp >= nrp) return;
    int row0 = rp * 256;
    int col0 = cp * 128;

    // ---- staging: 128B-per-row segments. GL16 g: 8 rows x 8 lanes x 16B.
    // A: wave w stages rows [w*32, w*32+32) -> 4 GL16. B: rows [w*16,+16) -> 2.
    const short* aRow[4];
    int aOffD[4];
#pragma unroll
    for (int g = 0; g < 4; ++g) {
        int r = w * 32 + g * 8 + (lane >> 3);
        int gr = row0 + r; if (gr >= M) gr = M - 1;
        int sch = (lane & 7) ^ (r & 7);             // pre-swizzled source chunk
        aRow[g] = A + (size_t)gr * 512 + sch * 8;
        aOffD[g] = (w * 32 + g * 8) * 64;           // wave-uniform dest (shorts)
    }
    const short* bRow[2];
    int bOffD[2];
#pragma unroll
    for (int g = 0; g < 2; ++g) {
        int r = w * 16 + g * 8 + (lane >> 3);
        int sch = (lane & 7) ^ (r & 7);
        bRow[g] = WT + (size_t)(col0 + r) * 512 + sch * 8;
        bOffD[g] = (w * 16 + g * 8) * 64;
    }

    // ---- swizzled ds_read offsets (shorts), fixed across tiles ----
    int aOff[2][4], bOff[2][4];
#pragma unroll
    for (int p = 0; p < 2; ++p) {
#pragma unroll
        for (int mi = 0; mi < 4; ++mi) {
            int r = wm * 64 + mi * 16 + (lane & 15);
            aOff[p][mi] = r * 64 + (((p * 4 + (lane >> 4)) ^ (r & 7)) * 8);
        }
#pragma unroll
        for (int ni = 0; ni < 4; ++ni) {
            int c = wn * 64 + ni * 16 + (lane & 15);
            bOff[p][ni] = c * 64 + (((p * 4 + (lane >> 4)) ^ (c & 7)) * 8);
        }
    }

    f32x4 acc[4][4] = {};

    auto stage = [&](int buf, int k0) {   // 6 GL16/wave, 1KB contiguous dest each
#pragma unroll
        for (int g = 0; g < 4; ++g) GL16(aRow[g] + k0, &As[buf * 16384 + aOffD[g]]);
#pragma unroll
        for (int g = 0; g < 2; ++g) GL16(bRow[g] + k0, &Bs[buf * 8192 + bOffD[g]]);
    };
    auto compute = [&](int buf) {
#pragma unroll
        for (int p = 0; p < 2; ++p) {
            s16x8 av[4], bv[4];
#pragma unroll
            for (int mi = 0; mi < 4; ++mi) av[mi] = *(const s16x8*)&As[buf * 16384 + aOff[p][mi]];
#pragma unroll
            for (int ni = 0; ni < 4; ++ni) bv[ni] = *(const s16x8*)&Bs[buf * 8192 + bOff[p][ni]];
#pragma unroll
            for (int mi = 0; mi < 4; ++mi)
#pragma unroll
                for (int ni = 0; ni < 4; ++ni)
                    acc[mi][ni] = __builtin_amdgcn_mfma_f32_16x16x32_bf16(av[mi], bv[ni], acc[mi][ni], 0, 0, 0);
        }
    };

    // depth-2 prologue: tiles 0 and 1 in flight (12 outstanding)
    stage(0, 0);
    stage(1, 64);
    int buf = 0;
#pragma unroll 1
    for (int t = 0; t < 8; ++t) {
        if (t + 2 < 8) {
            int b2 = buf + 2; if (b2 >= 3) b2 -= 3;
            stage(b2, (t + 2) * 64);                            // 18 outstanding
            asm volatile("s_waitcnt vmcnt(12)" ::: "memory");   // tile t retired
        } else if (t + 1 < 8) {
            asm volatile("s_waitcnt vmcnt(6)" ::: "memory");    // tile 6 retired
        } else {
            asm volatile("s_waitcnt vmcnt(0)" ::: "memory");    // tile 7 retired
        }
        __builtin_amdgcn_s_barrier();            // tile t staged for everyone
        __builtin_amdgcn_sched_barrier(0);
        compute(buf);
        __builtin_amdgcn_sched_barrier(0);
        __builtin_amdgcn_s_barrier();            // everyone done reading tile t
        __builtin_amdgcn_sched_barrier(0);
        ++buf; if (buf == 3) buf = 0;
    }

    int rbase = row0 + wm * 64;
    int cbase = col0 + wn * 64;
#pragma unroll
    for (int mi = 0; mi < 4; ++mi) {
#pragma unroll
        for (int r = 0; r < 4; ++r) {
            int row = rbase + mi * 16 + (lane >> 4) * 4 + r;
            if (row >= M) continue;
            float d = dis[row];
            float a20 = 0.f, a21 = 0.f, a22 = 0.f;
            if (A2) { a20 = A2[row*3+0]; a21 = A2[row*3+1]; a22 = A2[row*3+2]; }
#pragma unroll
            for (int ni = 0; ni < 4; ++ni) {
                int col = cbase + ni * 16 + (lane & 15);
                float v = acc[mi][ni][r];
                if (A2) v += a20 * W2[col] + a21 * W2[512 + col] + a22 * W2[1024 + col];
                C[(size_t)row * 512 + col] = f2b(d * v);
            }
        }
    }
}

// out[i,:] = bf16(relu( dis[i]*(sum_nbr B[src,:] + B[i,:]) + bias ))
// one wave/node; 4-edge windowed gather for memory-level parallelism
__global__ __launch_bounds__(256) void spmm512_kernel(
        const short* __restrict__ B, const int* __restrict__ rowptr, const int* __restrict__ esrc,
        const float* __restrict__ dis, const float* __restrict__ bias,
        short* __restrict__ out, int M) {
    int node = blockIdx.x * 4 + (threadIdx.x >> 6);
    int lane = threadIdx.x & 63;
    if (node >= M) return;
    const s16x8* Bv = (const s16x8*)B;
    s16x8 v = Bv[(size_t)node * 64 + lane];   // self loop
    float acc[8];
#pragma unroll
    for (int j = 0; j < 8; ++j) acc[j] = b2f(v[j]);
    int s = rowptr[node], e = rowptr[node + 1];
    int p = s;
    for (; p + 4 <= e; p += 4) {
        int s0 = esrc[p], s1 = esrc[p+1], s2 = esrc[p+2], s3 = esrc[p+3];
        s16x8 t0 = Bv[(size_t)s0 * 64 + lane];
        s16x8 t1 = Bv[(size_t)s1 * 64 + lane];
        s16x8 t2 = Bv[(size_t)s2 * 64 + lane];
        s16x8 t3 = Bv[(size_t)s3 * 64 + lane];
#pragma unroll
        for (int j = 0; j < 8; ++j)
            acc[j] += (b2f(t0[j]) + b2f(t1[j])) + (b2f(t2[j]) + b2f(t3[j]));
    }
    for (; p < e; ++p) {
        int src = esrc[p];
        s16x8 t = Bv[(size_t)src * 64 + lane];
#pragma unroll
        for (int j = 0; j < 8; ++j) acc[j] += b2f(t[j]);
    }
    float d = dis[node];
    const float4* bp = (const float4*)bias;
    float4 bb0 = bp[lane * 2], bb1 = bp[lane * 2 + 1];
    float r[8];
    r[0] = d*acc[0] + bb0.x; r[1] = d*acc[1] + bb0.y; r[2] = d*acc[2] + bb0.z; r[3] = d*acc[3] + bb0.w;
    r[4] = d*acc[4] + bb1.x; r[5] = d*acc[5] + bb1.y; r[6] = d*acc[6] + bb1.z; r[7] = d*acc[7] + bb1.w;
    s16x8 o;
#pragma unroll
    for (int j = 0; j < 8; ++j) o[j] = f2b(fmaxf(r[j], 0.f));
    ((s16x8*)out)[(size_t)node * 64 + lane] = o;
}

// final GEMM: B3[M,3] = dis .* (A_bf16[M,512] @ W[512,3]); one wave per row
__global__ __launch_bounds__(256) void gemm_n3_kernel(
        const short* __restrict__ A, const float* __restrict__ W,
        const float* __restrict__ dis, float* __restrict__ B3, int M) {
    int wid = (blockIdx.x * 256 + threadIdx.x) >> 6;
    int lane = threadIdx.x & 63;
    if (wid >= M) return;
    s16x8 v = ((const s16x8*)A)[(size_t)wid * 64 + lane];
    float s0 = 0.f, s1 = 0.f, s2 = 0.f;
#pragma unroll
    for (int j = 0; j < 8; ++j) {
        float a = b2f(v[j]);
        int k = lane * 8 + j;
        s0 += a * W[k*3+0];
        s1 += a * W[k*3+1];
        s2 += a * W[k*3+2];
    }
    for (int off = 32; off > 0; off >>= 1) {
        s0 += __shfl_down(s0, off);
        s1 += __shfl_down(s1, off);
        s2 += __shfl_down(s2, off);
    }
    if (lane == 0) {
        float d = dis[wid];
        B3[wid*3+0] = d * s0;
        B3[wid*3+1] = d * s1;
        B3[wid*3+2] = d * s2;
    }
}

__global__ void spmm3_kernel(const float* __restrict__ B3, const int* __restrict__ rowptr,
                             const int* __restrict__ esrc, const float* __restrict__ dis,
                             const float* __restrict__ bias, float* __restrict__ out, int M) {
    int i = blockIdx.x * 256 + threadIdx.x;
    if (i >= M) return;
    float a0 = B3[i*3+0], a1 = B3[i*3+1], a2 = B3[i*3+2];
    int s = rowptr[i], e = rowptr[i + 1];
    for (int p = s; p < e; ++p) {
        int src = esrc[p];
        a0 += B3[src*3+0];
        a1 += B3[src*3+1];
        a2 += B3[src*3+2];
    }
    float d = dis[i];
    out[i*3+0] = d * a0 + bias[0];
    out[i*3+1] = d * a1 + bias[1];
    out[i*3+2] = d * a2 + bias[2];
}

// KNN interpolate: block = 64 fine nodes x 4 waves; wave w scans coarse chunk of 500.
__global__ __launch_bounds__(256) void knn_kernel(
        const float* __restrict__ x, const float* __restrict__ cpos,
        const float* __restrict__ cy, float* __restrict__ fy, int M) {
    __shared__ float sd[12][64];
    __shared__ int   si[12][64];
    int lane = threadIdx.x & 63;
    int w = threadIdx.x >> 6;
    int gi = blockIdx.x * 64 + lane;
    int i = (gi < M) ? gi : (M - 1);
    float px = x[i*5+0], py = x[i*5+1];
    float pn2 = px*px + py*py;
    float d0 = 3.0e38f, d1 = 3.0e38f, d2 = 3.0e38f;
    int i0 = 0x7fffffff, i1 = 0x7fffffff, i2 = 0x7fffffff;
    int c0 = w * (N_COARSE / 4), c1 = c0 + (N_COARSE / 4);
    for (int c = c0; c < c1; ++c) {
        float a = cpos[c*2+0], b = cpos[c*2+1];
        float sn2 = a*a + b*b;                       // ref formula
        float d = pn2 + sn2 - 2.f * (px * a + py * b);
        if (d < d2) {
            if (d < d1) {
                d2 = d1; i2 = i1;
                if (d < d0) { d1 = d0; i1 = i0; d0 = d; i0 = c; }
                else       { d1 = d;  i1 = c; }
            } else { d2 = d; i2 = c; }
        }
    }
    sd[w*3+0][lane] = d0; si[w*3+0][lane] = i0;
    sd[w*3+1][lane] = d1; si[w*3+1][lane] = i1;
    sd[w*3+2][lane] = d2; si[w*3+2][lane] = i2;
    __syncthreads();
    if (w != 0 || gi >= M) return;
    float cd[12]; int ci[12];
#pragma unroll
    for (int q = 0; q < 12; ++q) { cd[q] = sd[q][lane]; ci[q] = si[q][lane]; }
    float bd[3]; int bi[3];
#pragma unroll
    for (int s = 0; s < 3; ++s) {
        float best = 3.4e38f; int besti = 0x7fffffff; int bq = 0;
#pragma unroll
        for (int q = 0; q < 12; ++q) {
            bool better = (cd[q] < best) || (cd[q] == best && ci[q] < besti);
            if (better) { best = cd[q]; besti = ci[q]; bq = q; }
        }
        bd[s] = best; bi[s] = besti;
        cd[bq] = 3.4e38f; ci[bq] = 0x7fffffff;
    }
    float w0 = 1.f / fmaxf(bd[0], 1e-16f);
    float w1 = 1.f / fmaxf(bd[1], 1e-16f);
    float w2 = 1.f / fmaxf(bd[2], 1e-16f);
    float ws = w0 + w1 + w2;
    int j0 = bi[0], j1 = bi[1], j2 = bi[2];
#pragma unroll
    for (int j = 0; j < 3; ++j) {
        float v = w0 * cy[j0*3+j] + w1 * cy[j1*3+j] + w2 * cy[j2*3+j];
        fy[gi*3+j] = v / ws;
    }
}

// ---------------- launch ----------------

extern "C" void kernel_launch(void* const* d_in, const int* in_sizes, int n_in,
                              void* d_out, int out_size, void* d_ws, size_t ws_size,
                              hipStream_t stream) {
    const float* x        = (const float*)d_in[0];
    const float* sdf      = (const float*)d_in[1];
    const float* coarse_x = (const float*)d_in[2];
    const float* coarse_y = (const float*)d_in[3];
    const int*   eidx     = (const int*)d_in[4];
    const float* pre_W0   = (const float*)d_in[5];
    const float* pre_b0   = (const float*)d_in[6];
    const float* pre_W1   = (const float*)d_in[7];
    const float* pre_b1   = (const float*)d_in[8];
    const float* pre_W2   = (const float*)d_in[9];
    const float* pre_b2   = (const float*)d_in[10];
    const float* end_W0   = (const float*)d_in[11];
    const float* end_b0   = (const float*)d_in[12];
    const float* end_W1   = (const float*)d_in[13];
    const float* end_b1   = (const float*)d_in[14];
    const float* end_W2   = (const float*)d_in[15];
    const float* end_b2   = (const float*)d_in[16];
    float* out = (float*)d_out;

    const int M = N_FINE, NE = N_EDGES;
    const int* erow = eidx;
    const int* ecol = eidx + NE;

    char* base = (char*)d_ws;
    size_t off = 0;
    auto alloc = [&](size_t bytes) { char* p = base + off; off = (off + bytes + 255) & ~(size_t)255; return p; };
    int*   counts = (int*)  alloc((size_t)M * 4);
    int*   rowptr = (int*)  alloc((size_t)(M + 1) * 4);
    int*   cursor = (int*)  alloc((size_t)M * 4);
    int*   esrc   = (int*)  alloc((size_t)NE * 4);
    int*   blksum = (int*)  alloc((size_t)64 * 4);
    float* dis    = (float*)alloc((size_t)M * 4);
    float* fy     = (float*)alloc((size_t)M * 3 * 4);
    float* B3     = (float*)alloc((size_t)M * 3 * 4);
    short* WT1    = (short*)alloc((size_t)512 * 512 * 2);
    short* WT2    = (short*)alloc((size_t)512 * 512 * 2);
    short* WT3    = (short*)alloc((size_t)512 * 512 * 2);
    short* WT4    = (short*)alloc((size_t)512 * 512 * 2);
    short* bufA   = (short*)alloc((size_t)M * 512 * 2);
    short* bufB   = (short*)alloc((size_t)M * 512 * 2);
    (void)ws_size;

    // weight prep (one launch, 4 matrices)
    wt4_kernel<<<dim3(256, 4), 256, 0, stream>>>(pre_W1, pre_W2, end_W0 + 3 * 512, end_W1,
                                                 WT1, WT2, WT3, WT4);

    // CSR + degrees
    hipMemsetAsync(counts, 0, (size_t)M * 4, stream);
    count_edges_kernel<<<cdiv(NE, 256), 256, 0, stream>>>(ecol, counts, NE);
    compute_dis_kernel<<<cdiv(M, 256), 256, 0, stream>>>(counts, dis, M);
    int nb = cdiv(M, 1024);
    scan_block_kernel<<<nb, 1024, 0, stream>>>(counts, rowptr, blksum, M);
    scan_tops_kernel<<<1, 64, 0, stream>>>(blksum, nb);
    scan_add_kernel<<<cdiv(M + 1, 256), 256, 0, stream>>>(rowptr, blksum, M);
    hipMemcpyAsync(cursor, rowptr, (size_t)M * 4, hipMemcpyDeviceToDevice, stream);
    scatter_edges_kernel<<<cdiv(NE, 256), 256, 0, stream>>>(erow, ecol, cursor, esrc, NE);

    // KNN interpolate
    knn_kernel<<<cdiv(M, 64), 256, 0, stream>>>(x, coarse_x, coarse_y, fy, M);

    // gemm grid: 196 row-panels(256) x 4 col-panels(128); id=(rp>>3)*32+cp*8+(rp&7)
    int nrp = cdiv(M, 256);
    int ggrid = cdiv(nrp, 8) * 32;
    int sgrid = cdiv(M, 4);

    pre0_kernel<<<cdiv(M * 64, 256), 256, 0, stream>>>(x, sdf, pre_W0, dis, bufB, M);
    spmm512_kernel<<<sgrid, 256, 0, stream>>>(bufB, rowptr, esrc, dis, pre_b0, bufA, M);

    gemm512_mfma_kernel<<<ggrid, 512, 0, stream>>>(bufA, WT1, dis, bufB, M, nullptr, nullptr);
    spmm512_kernel<<<sgrid, 256, 0, stream>>>(bufB, rowptr, esrc, dis, pre_b1, bufA, M);

    gemm512_mfma_kernel<<<ggrid, 512, 0, stream>>>(bufA, WT2, dis, bufB, M, nullptr, nullptr);
    spmm512_kernel<<<sgrid, 256, 0, stream>>>(bufB, rowptr, esrc, dis, pre_b2, bufA, M);

    gemm512_mfma_kernel<<<ggrid, 512, 0, stream>>>(bufA, WT3, dis, bufB, M, fy, end_W0);
    spmm512_kernel<<<sgrid, 256, 0, stream>>>(bufB, rowptr, esrc, dis, end_b0, bufA, M);

    gemm512_mfma_kernel<<<ggrid, 512, 0, stream>>>(bufA, WT4, dis, bufB, M, nullptr, nullptr);
    spmm512_kernel<<<sgrid, 256, 0, stream>>>(bufB, rowptr, esrc, dis, end_b1, bufA, M);

    gemm_n3_kernel<<<cdiv(M * 64, 256), 256, 0, stream>>>(bufA, end_W2, dis, B3, M);
    spmm3_kernel<<<cdiv(M, 256), 256, 0, stream>>>(B3, rowptr, esrc, dis, end_b2, out, M);
}

// Round 14
// 676.819 us; speedup vs baseline: 1.4025x; 1.0698x over previous
//
#include <hip/hip_runtime.h>
#include <hip/hip_bf16.h>

#define N_FINE 50000
#define N_COARSE 2000
#define N_EDGES 300000

typedef short  s16x8 __attribute__((ext_vector_type(8)));
typedef float  f32x4 __attribute__((ext_vector_type(4)));

static inline int cdiv(int a, int b) { return (a + b - 1) / b; }

__device__ __forceinline__ short f2b(float f) {      // f32 -> bf16 RNE
    unsigned u = __builtin_bit_cast(unsigned, f);
    unsigned r = (u + 0x7fffu + ((u >> 16) & 1u)) >> 16;
    return (short)r;
}
__device__ __forceinline__ float b2f(short s) {
    return __builtin_bit_cast(float, ((unsigned)(unsigned short)s) << 16);
}

#define GL16(gsrc, ldst) __builtin_amdgcn_global_load_lds( \
    (const __attribute__((address_space(1))) unsigned*)(gsrc), \
    (__attribute__((address_space(3))) unsigned*)(ldst), 16, 0, 0)

// XCD-affinity block remap for node-parallel kernels: block b covers nodes
// [b*4, b*4+4); panel g = 128 nodes = 32 blocks; panel g must run on XCD g%8
// to match gemm's rp%8 row-panel mapping (producer-consumer L2 locality).
// id -> (g, j): g = (id>>8)*8 + (id&7), j = (id>>3)&31, b = g*32 + j. Bijective.
__device__ __forceinline__ int xcd_node_block(int id) {
    int g = ((id >> 8) << 3) | (id & 7);
    int j = (id >> 3) & 31;
    return g * 32 + j;
}

// ---------------- CSR build ----------------

__global__ void count_edges_kernel(const int* __restrict__ col, int* __restrict__ counts, int ne) {
    int e = blockIdx.x * 256 + threadIdx.x;
    if (e < ne) atomicAdd(&counts[col[e]], 1);
}

__global__ void compute_dis_kernel(const int* __restrict__ counts, float* __restrict__ dis, int n) {
    int i = blockIdx.x * 256 + threadIdx.x;
    if (i < n) dis[i] = rsqrtf((float)(counts[i] + 1));   // +1 self loop
}

// two-level scan: per-block 1024-wide exclusive scan + block totals
__global__ __launch_bounds__(1024) void scan_block_kernel(const int* __restrict__ counts,
        int* __restrict__ rowptr, int* __restrict__ blksum, int n) {
    __shared__ int wsum[16];
    int tid = threadIdx.x, lane = tid & 63, wv = tid >> 6;
    int i = blockIdx.x * 1024 + tid;
    int v = (i < n) ? counts[i] : 0;
    int x = v;
#pragma unroll
    for (int off = 1; off < 64; off <<= 1) {
        int t = __shfl_up(x, off);
        if (lane >= off) x += t;
    }
    if (lane == 63) wsum[wv] = x;
    __syncthreads();
    if (wv == 0) {
        int s = (lane < 16) ? wsum[lane] : 0;
#pragma unroll
        for (int off = 1; off < 16; off <<= 1) {
            int t = __shfl_up(s, off);
            if (lane >= off) s += t;
        }
        if (lane < 16) wsum[lane] = s;
    }
    __syncthreads();
    int prefix = (wv > 0) ? wsum[wv - 1] : 0;
    int incl = prefix + x;
    if (i < n) rowptr[i] = incl - v;   // exclusive
    if (tid == 1023) blksum[blockIdx.x] = incl;
}

__global__ void scan_tops_kernel(int* __restrict__ blksum, int nb) {
    int lane = threadIdx.x;
    int v = (lane < nb) ? blksum[lane] : 0;
    int x = v;
#pragma unroll
    for (int off = 1; off < 64; off <<= 1) {
        int t = __shfl_up(x, off);
        if (lane >= off) x += t;
    }
    if (lane < nb) blksum[lane] = x - v;
}

__global__ void scan_add_kernel(int* __restrict__ rowptr, const int* __restrict__ blksum, int n) {
    int i = blockIdx.x * 256 + threadIdx.x;
    if (i < n) rowptr[i] += blksum[i >> 10];
    else if (i == n) rowptr[n] = N_EDGES;
}

__global__ void scatter_edges_kernel(const int* __restrict__ row, const int* __restrict__ col,
                                     int* __restrict__ cursor, int* __restrict__ esrc, int ne) {
    int e = blockIdx.x * 256 + threadIdx.x;
    if (e < ne) {
        int p = atomicAdd(&cursor[col[e]], 1);
        esrc[p] = row[e];
    }
}

// ---------------- weight prep: WT[n][k] = bf16(W[k][n]), 512x512, LDS-tiled ----------------

__global__ __launch_bounds__(256) void wt4_kernel(
        const float* __restrict__ W0, const float* __restrict__ W1,
        const float* __restrict__ W2, const float* __restrict__ W3,
        short* __restrict__ T0, short* __restrict__ T1,
        short* __restrict__ T2, short* __restrict__ T3) {
    __shared__ float tile[32][33];
    const float* W; short* WT;
    switch (blockIdx.y) {
        case 0: W = W0; WT = T0; break;
        case 1: W = W1; WT = T1; break;
        case 2: W = W2; WT = T2; break;
        default: W = W3; WT = T3; break;
    }
    int bx = blockIdx.x & 15;        // k-tile
    int by = blockIdx.x >> 4;        // n-tile
    int tx = threadIdx.x & 31;
    int ty = threadIdx.x >> 5;
#pragma unroll
    for (int i = 0; i < 4; ++i) {
        int k = bx * 32 + ty + i * 8;
        int n = by * 32 + tx;
        tile[ty + i * 8][tx] = W[(size_t)k * 512 + n];   // coalesced load
    }
    __syncthreads();
#pragma unroll
    for (int i = 0; i < 4; ++i) {
        int n = by * 32 + ty + i * 8;
        int k = bx * 32 + tx;
        WT[(size_t)n * 512 + k] = f2b(tile[tx][ty + i * 8]);  // coalesced store
    }
}

// ---------------- layer kernels ----------------

// first layer: [M,6] @ [6,512], scaled by dis, bf16 out; XCD-affine block map
__global__ void pre0_kernel(const float* __restrict__ x, const float* __restrict__ sdf,
                            const float* __restrict__ W, const float* __restrict__ dis,
                            short* __restrict__ B, int M) {
    int b = xcd_node_block(blockIdx.x);
    int m = b * 4 + (threadIdx.x >> 6);
    int n8 = (threadIdx.x & 63) << 3;
    if (m >= M) return;
    float a0 = x[m*5+0], a1 = x[m*5+1], a2 = x[m*5+2], a3 = x[m*5+3], a4 = x[m*5+4], a5 = sdf[m];
    float d = dis[m];
    s16x8 o;
#pragma unroll
    for (int j = 0; j < 8; ++j) {
        int n = n8 + j;
        float t = a0*W[n] + a1*W[512+n] + a2*W[1024+n] + a3*W[1536+n] + a4*W[2048+n] + a5*W[2560+n];
        o[j] = f2b(d * t);
    }
    *(s16x8*)&B[(size_t)m*512 + n8] = o;
}

// MFMA GEMM v5 (r10 verbatim -- best measured 91 us): 128x128 tile, BK=32,
// 16 K-tiles, 3 LDS buffers, depth-2 counted-vmcnt prefetch, chunk-XOR
// swizzle both sides, XCD map rp%8 (row-panel locality).
__global__ __launch_bounds__(256) void gemm512_mfma_kernel(
        const short* __restrict__ A, const short* __restrict__ WT,
        const float* __restrict__ dis, short* __restrict__ C, int M,
        const float* __restrict__ A2, const float* __restrict__ W2) {
    __shared__ __attribute__((aligned(16))) short As[3][128 * 32];   // 3 x 8 KB
    __shared__ __attribute__((aligned(16))) short Bs[3][128 * 32];   // 3 x 8 KB
    int tid  = threadIdx.x;
    int lane = tid & 63;
    int w    = tid >> 6;          // 0..3
    int wr   = w >> 1, wc = w & 1;

    int nrp = (M + 127) >> 7;     // 391 row-panels
    int id = blockIdx.x;
    int rp = (id >> 5) * 8 + (id & 7);   // id&7 fixed per rp -> same XCD
    int cp = (id >> 3) & 3;              // col-panel 0..3
    if (rp >= nrp) return;
    int row0 = rp * 128;
    int col0 = cp * 128;

    // ---- staging: wave w stages rows [w*32, w*32+32): 2 GL16 per matrix ----
    const short* aRow[2];
    const short* bRow[2];
    int ldsOff[2];
#pragma unroll
    for (int g = 0; g < 2; ++g) {
        int r = w * 32 + g * 16 + (lane >> 2);
        int ar = row0 + r; if (ar >= M) ar = M - 1;
        int sch = (lane & 3) ^ ((r >> 1) & 3);      // pre-swizzled source chunk
        aRow[g] = A  + (size_t)ar * 512 + sch * 8;
        bRow[g] = WT + (size_t)(col0 + r) * 512 + sch * 8;
        ldsOff[g] = (w * 32 + g * 16) * 32;         // wave-uniform (shorts)
    }

    // ---- swizzled ds_read offsets (shorts), fixed across tiles ----
    int ks = lane >> 4;           // k-slot 0..3 (8 shorts each)
    int aOff[4], bOff[4];
#pragma unroll
    for (int mi = 0; mi < 4; ++mi) {
        int r = wr * 64 + mi * 16 + (lane & 15);
        aOff[mi] = r * 32 + ((ks ^ ((r >> 1) & 3)) * 8);
    }
#pragma unroll
    for (int ni = 0; ni < 4; ++ni) {
        int c = wc * 64 + ni * 16 + (lane & 15);
        bOff[ni] = c * 32 + ((ks ^ ((c >> 1) & 3)) * 8);
    }

    f32x4 acc[4][4] = {};

    auto stage = [&](int buf, int k0) {   // 4 GL16/wave
#pragma unroll
        for (int g = 0; g < 2; ++g) {
            GL16(aRow[g] + k0, &As[buf][ldsOff[g]]);
            GL16(bRow[g] + k0, &Bs[buf][ldsOff[g]]);
        }
    };
    auto compute = [&](int buf) {
        s16x8 av[4], bv[4];
#pragma unroll
        for (int mi = 0; mi < 4; ++mi) av[mi] = *(const s16x8*)&As[buf][aOff[mi]];
#pragma unroll
        for (int ni = 0; ni < 4; ++ni) bv[ni] = *(const s16x8*)&Bs[buf][bOff[ni]];
#pragma unroll
        for (int mi = 0; mi < 4; ++mi)
#pragma unroll
            for (int ni = 0; ni < 4; ++ni)
                acc[mi][ni] = __builtin_amdgcn_mfma_f32_16x16x32_bf16(av[mi], bv[ni], acc[mi][ni], 0, 0, 0);
    };

    // depth-2 prologue: tiles 0 and 1 in flight
    stage(0, 0);
    stage(1, 32);
    int buf = 0;
#pragma unroll 1
    for (int t = 0; t < 16; ++t) {
        if (t + 2 < 16) {
            int b2 = buf + 2; if (b2 >= 3) b2 -= 3;
            stage(b2, (t + 2) * 32);                           // keep 2 tiles in flight
            asm volatile("s_waitcnt vmcnt(8)" ::: "memory");   // tile t retired (in-order)
        } else if (t + 1 < 16) {
            asm volatile("s_waitcnt vmcnt(4)" ::: "memory");   // tile 14 retired
        } else {
            asm volatile("s_waitcnt vmcnt(0)" ::: "memory");   // tile 15 retired
        }
        __builtin_amdgcn_s_barrier();            // tile t staged for everyone
        __builtin_amdgcn_sched_barrier(0);
        compute(buf);
        __builtin_amdgcn_sched_barrier(0);
        __builtin_amdgcn_s_barrier();            // everyone done reading tile t
        __builtin_amdgcn_sched_barrier(0);
        ++buf; if (buf == 3) buf = 0;
    }

    int rbase = row0 + wr * 64;
    int cbase = col0 + wc * 64;
#pragma unroll
    for (int mi = 0; mi < 4; ++mi) {
#pragma unroll
        for (int r = 0; r < 4; ++r) {
            int row = rbase + mi * 16 + (lane >> 4) * 4 + r;
            if (row >= M) continue;
            float d = dis[row];
            float a20 = 0.f, a21 = 0.f, a22 = 0.f;
            if (A2) { a20 = A2[row*3+0]; a21 = A2[row*3+1]; a22 = A2[row*3+2]; }
#pragma unroll
            for (int ni = 0; ni < 4; ++ni) {
                int col = cbase + ni * 16 + (lane & 15);
                float v = acc[mi][ni][r];
                if (A2) v += a20 * W2[col] + a21 * W2[512 + col] + a22 * W2[1024 + col];
                C[(size_t)row * 512 + col] = f2b(d * v);
            }
        }
    }
}

// out[i,:] = bf16(relu( dis[i]*(sum_nbr B[src,:] + B[i,:]) + bias ))
// one wave/node; 4-edge window; XCD-affine block map (matches gemm rp%8)
__global__ __launch_bounds__(256) void spmm512_kernel(
        const short* __restrict__ B, const int* __restrict__ rowptr, const int* __restrict__ esrc,
        const float* __restrict__ dis, const float* __restrict__ bias,
        short* __restrict__ out, int M) {
    int b = xcd_node_block(blockIdx.x);
    int node = b * 4 + (threadIdx.x >> 6);
    int lane = threadIdx.x & 63;
    if (node >= M) return;
    const s16x8* Bv = (const s16x8*)B;
    s16x8 v = Bv[(size_t)node * 64 + lane];   // self loop
    float acc[8];
#pragma unroll
    for (int j = 0; j < 8; ++j) acc[j] = b2f(v[j]);
    int s = rowptr[node], e = rowptr[node + 1];
    int p = s;
    for (; p + 4 <= e; p += 4) {
        int s0 = esrc[p], s1 = esrc[p+1], s2 = esrc[p+2], s3 = esrc[p+3];
        s16x8 t0 = Bv[(size_t)s0 * 64 + lane];
        s16x8 t1 = Bv[(size_t)s1 * 64 + lane];
        s16x8 t2 = Bv[(size_t)s2 * 64 + lane];
        s16x8 t3 = Bv[(size_t)s3 * 64 + lane];
#pragma unroll
        for (int j = 0; j < 8; ++j)
            acc[j] += (b2f(t0[j]) + b2f(t1[j])) + (b2f(t2[j]) + b2f(t3[j]));
    }
    for (; p < e; ++p) {
        int src = esrc[p];
        s16x8 t = Bv[(size_t)src * 64 + lane];
#pragma unroll
        for (int j = 0; j < 8; ++j) acc[j] += b2f(t[j]);
    }
    float d = dis[node];
    const float4* bp = (const float4*)bias;
    float4 bb0 = bp[lane * 2], bb1 = bp[lane * 2 + 1];
    float r[8];
    r[0] = d*acc[0] + bb0.x; r[1] = d*acc[1] + bb0.y; r[2] = d*acc[2] + bb0.z; r[3] = d*acc[3] + bb0.w;
    r[4] = d*acc[4] + bb1.x; r[5] = d*acc[5] + bb1.y; r[6] = d*acc[6] + bb1.z; r[7] = d*acc[7] + bb1.w;
    s16x8 o;
#pragma unroll
    for (int j = 0; j < 8; ++j) o[j] = f2b(fmaxf(r[j], 0.f));
    ((s16x8*)out)[(size_t)node * 64 + lane] = o;
}

// final GEMM: B3[M,3] = dis .* (A_bf16[M,512] @ W[512,3]); one wave per row
__global__ __launch_bounds__(256) void gemm_n3_kernel(
        const short* __restrict__ A, const float* __restrict__ W,
        const float* __restrict__ dis, float* __restrict__ B3, int M) {
    int wid = (blockIdx.x * 256 + threadIdx.x) >> 6;
    int lane = threadIdx.x & 63;
    if (wid >= M) return;
    s16x8 v = ((const s16x8*)A)[(size_t)wid * 64 + lane];
    float s0 = 0.f, s1 = 0.f, s2 = 0.f;
#pragma unroll
    for (int j = 0; j < 8; ++j) {
        float a = b2f(v[j]);
        int k = lane * 8 + j;
        s0 += a * W[k*3+0];
        s1 += a * W[k*3+1];
        s2 += a * W[k*3+2];
    }
    for (int off = 32; off > 0; off >>= 1) {
        s0 += __shfl_down(s0, off);
        s1 += __shfl_down(s1, off);
        s2 += __shfl_down(s2, off);
    }
    if (lane == 0) {
        float d = dis[wid];
        B3[wid*3+0] = d * s0;
        B3[wid*3+1] = d * s1;
        B3[wid*3+2] = d * s2;
    }
}

__global__ void spmm3_kernel(const float* __restrict__ B3, const int* __restrict__ rowptr,
                             const int* __restrict__ esrc, const float* __restrict__ dis,
                             const float* __restrict__ bias, float* __restrict__ out, int M) {
    int i = blockIdx.x * 256 + threadIdx.x;
    if (i >= M) return;
    float a0 = B3[i*3+0], a1 = B3[i*3+1], a2 = B3[i*3+2];
    int s = rowptr[i], e = rowptr[i + 1];
    for (int p = s; p < e; ++p) {
        int src = esrc[p];
        a0 += B3[src*3+0];
        a1 += B3[src*3+1];
        a2 += B3[src*3+2];
    }
    float d = dis[i];
    out[i*3+0] = d * a0 + bias[0];
    out[i*3+1] = d * a1 + bias[1];
    out[i*3+2] = d * a2 + bias[2];
}

// KNN interpolate: block = 64 fine nodes x 4 waves; wave w scans coarse chunk of 500.
__global__ __launch_bounds__(256) void knn_kernel(
        const float* __restrict__ x, const float* __restrict__ cpos,
        const float* __restrict__ cy, float* __restrict__ fy, int M) {
    __shared__ float sd[12][64];
    __shared__ int   si[12][64];
    int lane = threadIdx.x & 63;
    int w = threadIdx.x >> 6;
    int gi = blockIdx.x * 64 + lane;
    int i = (gi < M) ? gi : (M - 1);
    float px = x[i*5+0], py = x[i*5+1];
    float pn2 = px*px + py*py;
    float d0 = 3.0e38f, d1 = 3.0e38f, d2 = 3.0e38f;
    int i0 = 0x7fffffff, i1 = 0x7fffffff, i2 = 0x7fffffff;
    int c0 = w * (N_COARSE / 4), c1 = c0 + (N_COARSE / 4);
    for (int c = c0; c < c1; ++c) {
        float a = cpos[c*2+0], b = cpos[c*2+1];
        float sn2 = a*a + b*b;                       // ref formula
        float d = pn2 + sn2 - 2.f * (px * a + py * b);
        if (d < d2) {
            if (d < d1) {
                d2 = d1; i2 = i1;
                if (d < d0) { d1 = d0; i1 = i0; d0 = d; i0 = c; }
                else       { d1 = d;  i1 = c; }
            } else { d2 = d; i2 = c; }
        }
    }
    sd[w*3+0][lane] = d0; si[w*3+0][lane] = i0;
    sd[w*3+1][lane] = d1; si[w*3+1][lane] = i1;
    sd[w*3+2][lane] = d2; si[w*3+2][lane] = i2;
    __syncthreads();
    if (w != 0 || gi >= M) return;
    float cd[12]; int ci[12];
#pragma unroll
    for (int q = 0; q < 12; ++q) { cd[q] = sd[q][lane]; ci[q] = si[q][lane]; }
    float bd[3]; int bi[3];
#pragma unroll
    for (int s = 0; s < 3; ++s) {
        float best = 3.4e38f; int besti = 0x7fffffff; int bq = 0;
#pragma unroll
        for (int q = 0; q < 12; ++q) {
            bool better = (cd[q] < best) || (cd[q] == best && ci[q] < besti);
            if (better) { best = cd[q]; besti = ci[q]; bq = q; }
        }
        bd[s] = best; bi[s] = besti;
        cd[bq] = 3.4e38f; ci[bq] = 0x7fffffff;
    }
    float w0 = 1.f / fmaxf(bd[0], 1e-16f);
    float w1 = 1.f / fmaxf(bd[1], 1e-16f);
    float w2 = 1.f / fmaxf(bd[2], 1e-16f);
    float ws = w0 + w1 + w2;
    int j0 = bi[0], j1 = bi[1], j2 = bi[2];
#pragma unroll
    for (int j = 0; j < 3; ++j) {
        float v = w0 * cy[j0*3+j] + w1 * cy[j1*3+j] + w2 * cy[j2*3+j];
        fy[gi*3+j] = v / ws;
    }
}

// ---------------- launch ----------------

extern "C" void kernel_launch(void* const* d_in, const int* in_sizes, int n_in,
                              void* d_out, int out_size, void* d_ws, size_t ws_size,
                              hipStream_t stream) {
    const float* x        = (const float*)d_in[0];
    const float* sdf      = (const float*)d_in[1];
    const float* coarse_x = (const float*)d_in[2];
    const float* coarse_y = (const float*)d_in[3];
    const int*   eidx     = (const int*)d_in[4];
    const float* pre_W0   = (const float*)d_in[5];
    const float* pre_b0   = (const float*)d_in[6];
    const float* pre_W1   = (const float*)d_in[7];
    const float* pre_b1   = (const float*)d_in[8];
    const float* pre_W2   = (const float*)d_in[9];
    const float* pre_b2   = (const float*)d_in[10];
    const float* end_W0   = (const float*)d_in[11];
    const float* end_b0   = (const float*)d_in[12];
    const float* end_W1   = (const float*)d_in[13];
    const float* end_b1   = (const float*)d_in[14];
    const float* end_W2   = (const float*)d_in[15];
    const float* end_b2   = (const float*)d_in[16];
    float* out = (float*)d_out;

    const int M = N_FINE, NE = N_EDGES;
    const int* erow = eidx;
    const int* ecol = eidx + NE;

    char* base = (char*)d_ws;
    size_t off = 0;
    auto alloc = [&](size_t bytes) { char* p = base + off; off = (off + bytes + 255) & ~(size_t)255; return p; };
    int*   counts = (int*)  alloc((size_t)M * 4);
    int*   rowptr = (int*)  alloc((size_t)(M + 1) * 4);
    int*   cursor = (int*)  alloc((size_t)M * 4);
    int*   esrc   = (int*)  alloc((size_t)NE * 4);
    int*   blksum = (int*)  alloc((size_t)64 * 4);
    float* dis    = (float*)alloc((size_t)M * 4);
    float* fy     = (float*)alloc((size_t)M * 3 * 4);
    float* B3     = (float*)alloc((size_t)M * 3 * 4);
    short* WT1    = (short*)alloc((size_t)512 * 512 * 2);
    short* WT2    = (short*)alloc((size_t)512 * 512 * 2);
    short* WT3    = (short*)alloc((size_t)512 * 512 * 2);
    short* WT4    = (short*)alloc((size_t)512 * 512 * 2);
    short* bufA   = (short*)alloc((size_t)M * 512 * 2);
    short* bufB   = (short*)alloc((size_t)M * 512 * 2);
    (void)ws_size;

    // weight prep (one launch, 4 matrices)
    wt4_kernel<<<dim3(256, 4), 256, 0, stream>>>(pre_W1, pre_W2, end_W0 + 3 * 512, end_W1,
                                                 WT1, WT2, WT3, WT4);

    // CSR + degrees
    hipMemsetAsync(counts, 0, (size_t)M * 4, stream);
    count_edges_kernel<<<cdiv(NE, 256), 256, 0, stream>>>(ecol, counts, NE);
    compute_dis_kernel<<<cdiv(M, 256), 256, 0, stream>>>(counts, dis, M);
    int nb = cdiv(M, 1024);
    scan_block_kernel<<<nb, 1024, 0, stream>>>(counts, rowptr, blksum, M);
    scan_tops_kernel<<<1, 64, 0, stream>>>(blksum, nb);
    scan_add_kernel<<<cdiv(M + 1, 256), 256, 0, stream>>>(rowptr, blksum, M);
    hipMemcpyAsync(cursor, rowptr, (size_t)M * 4, hipMemcpyDeviceToDevice, stream);
    scatter_edges_kernel<<<cdiv(NE, 256), 256, 0, stream>>>(erow, ecol, cursor, esrc, NE);

    // KNN interpolate
    knn_kernel<<<cdiv(M, 64), 256, 0, stream>>>(x, coarse_x, coarse_y, fy, M);

    // gemm grid: 391 row-panels x 4 col-panels; id = (rp>>3)*32 + cp*8 + (rp&7)
    int nrp = cdiv(M, 128);
    int ggrid = cdiv(nrp, 8) * 32;
    // node-parallel grid (pre0/spmm): XCD-affine remap over 128-node panels
    int sgrid = cdiv(cdiv(M, 128), 8) * 256;   // 12544

    pre0_kernel<<<sgrid, 256, 0, stream>>>(x, sdf, pre_W0, dis, bufB, M);
    spmm512_kernel<<<sgrid, 256, 0, stream>>>(bufB, rowptr, esrc, dis, pre_b0, bufA, M);

    gemm512_mfma_kernel<<<ggrid, 256, 0, stream>>>(bufA, WT1, dis, bufB, M, nullptr, nullptr);
    spmm512_kernel<<<sgrid, 256, 0, stream>>>(bufB, rowptr, esrc, dis, pre_b1, bufA, M);

    gemm512_mfma_kernel<<<ggrid, 256, 0, stream>>>(bufA, WT2, dis, bufB, M, nullptr, nullptr);
    spmm512_kernel<<<sgrid, 256, 0, stream>>>(bufB, rowptr, esrc, dis, pre_b2, bufA, M);

    gemm512_mfma_kernel<<<ggrid, 256, 0, stream>>>(bufA, WT3, dis, bufB, M, fy, end_W0);
    spmm512_kernel<<<sgrid, 256, 0, stream>>>(bufB, rowptr, esrc, dis, end_b0, bufA, M);

    gemm512_mfma_kernel<<<ggrid, 256, 0, stream>>>(bufA, WT4, dis, bufB, M, nullptr, nullptr);
    spmm512_kernel<<<sgrid, 256, 0, stream>>>(bufB, rowptr, esrc, dis, end_b1, bufA, M);

    gemm_n3_kernel<<<cdiv(M * 64, 256), 256, 0, stream>>>(bufA, end_W2, dis, B3, M);
    spmm3_kernel<<<cdiv(M, 256), 256, 0, stream>>>(B3, rowptr, esrc, dis, end_b2, out, M);
}

// Round 15
// 669.602 us; speedup vs baseline: 1.4176x; 1.0108x over previous
//
#include <hip/hip_runtime.h>
#include <hip/hip_bf16.h>

#define N_FINE 50000
#define N_COARSE 2000
#define N_EDGES 300000

typedef short  s16x8 __attribute__((ext_vector_type(8)));
typedef float  f32x4 __attribute__((ext_vector_type(4)));

static inline int cdiv(int a, int b) { return (a + b - 1) / b; }

__device__ __forceinline__ short f2b(float f) {      // f32 -> bf16 RNE
    unsigned u = __builtin_bit_cast(unsigned, f);
    unsigned r = (u + 0x7fffu + ((u >> 16) & 1u)) >> 16;
    return (short)r;
}
__device__ __forceinline__ float b2f(short s) {
    return __builtin_bit_cast(float, ((unsigned)(unsigned short)s) << 16);
}

#define GL16(gsrc, ldst) __builtin_amdgcn_global_load_lds( \
    (const __attribute__((address_space(1))) unsigned*)(gsrc), \
    (__attribute__((address_space(3))) unsigned*)(ldst), 16, 0, 0)

// XCD-affinity block remap for node-parallel kernels (r14, kept: harmless,
// aligns producer/consumer panels on one XCD's L2).
__device__ __forceinline__ int xcd_node_block(int id) {
    int g = ((id >> 8) << 3) | (id & 7);
    int j = (id >> 3) & 31;
    return g * 32 + j;
}

// ---------------- CSR build ----------------

__global__ void count_edges_kernel(const int* __restrict__ col, int* __restrict__ counts, int ne) {
    int e = blockIdx.x * 256 + threadIdx.x;
    if (e < ne) atomicAdd(&counts[col[e]], 1);
}

// two-level scan: per-block 1024-wide exclusive scan + block totals.
// Also emits dis[i] = rsqrt(counts[i]+1)  (fused, was a separate pass).
__global__ __launch_bounds__(1024) void scan_block_kernel(const int* __restrict__ counts,
        int* __restrict__ rowptr, int* __restrict__ blksum, float* __restrict__ dis, int n) {
    __shared__ int wsum[16];
    int tid = threadIdx.x, lane = tid & 63, wv = tid >> 6;
    int i = blockIdx.x * 1024 + tid;
    int v = (i < n) ? counts[i] : 0;
    if (i < n) dis[i] = rsqrtf((float)(v + 1));   // +1 self loop
    int x = v;
#pragma unroll
    for (int off = 1; off < 64; off <<= 1) {
        int t = __shfl_up(x, off);
        if (lane >= off) x += t;
    }
    if (lane == 63) wsum[wv] = x;
    __syncthreads();
    if (wv == 0) {
        int s = (lane < 16) ? wsum[lane] : 0;
#pragma unroll
        for (int off = 1; off < 16; off <<= 1) {
            int t = __shfl_up(s, off);
            if (lane >= off) s += t;
        }
        if (lane < 16) wsum[lane] = s;
    }
    __syncthreads();
    int prefix = (wv > 0) ? wsum[wv - 1] : 0;
    int incl = prefix + x;
    if (i < n) rowptr[i] = incl - v;   // exclusive
    if (tid == 1023) blksum[blockIdx.x] = incl;
}

__global__ void scan_tops_kernel(int* __restrict__ blksum, int nb) {
    int lane = threadIdx.x;
    int v = (lane < nb) ? blksum[lane] : 0;
    int x = v;
#pragma unroll
    for (int off = 1; off < 64; off <<= 1) {
        int t = __shfl_up(x, off);
        if (lane >= off) x += t;
    }
    if (lane < nb) blksum[lane] = x - v;
}

// adds block prefix; also initializes cursor = rowptr (kills the d2d memcpy)
__global__ void scan_add_kernel(int* __restrict__ rowptr, int* __restrict__ cursor,
                                const int* __restrict__ blksum, int n) {
    int i = blockIdx.x * 256 + threadIdx.x;
    if (i < n) {
        int r = rowptr[i] + blksum[i >> 10];
        rowptr[i] = r;
        cursor[i] = r;
    } else if (i == n) {
        rowptr[n] = N_EDGES;
    }
}

__global__ void scatter_edges_kernel(const int* __restrict__ row, const int* __restrict__ col,
                                     int* __restrict__ cursor, int* __restrict__ esrc, int ne) {
    int e = blockIdx.x * 256 + threadIdx.x;
    if (e < ne) {
        int p = atomicAdd(&cursor[col[e]], 1);
        esrc[p] = row[e];
    }
}

// ---------------- weight prep: WT[n][k] = bf16(W[k][n]), 512x512, LDS-tiled ----------------

__global__ __launch_bounds__(256) void wt4_kernel(
        const float* __restrict__ W0, const float* __restrict__ W1,
        const float* __restrict__ W2, const float* __restrict__ W3,
        short* __restrict__ T0, short* __restrict__ T1,
        short* __restrict__ T2, short* __restrict__ T3) {
    __shared__ float tile[32][33];
    const float* W; short* WT;
    switch (blockIdx.y) {
        case 0: W = W0; WT = T0; break;
        case 1: W = W1; WT = T1; break;
        case 2: W = W2; WT = T2; break;
        default: W = W3; WT = T3; break;
    }
    int bx = blockIdx.x & 15;        // k-tile
    int by = blockIdx.x >> 4;        // n-tile
    int tx = threadIdx.x & 31;
    int ty = threadIdx.x >> 5;
#pragma unroll
    for (int i = 0; i < 4; ++i) {
        int k = bx * 32 + ty + i * 8;
        int n = by * 32 + tx;
        tile[ty + i * 8][tx] = W[(size_t)k * 512 + n];   // coalesced load
    }
    __syncthreads();
#pragma unroll
    for (int i = 0; i < 4; ++i) {
        int n = by * 32 + ty + i * 8;
        int k = bx * 32 + tx;
        WT[(size_t)n * 512 + k] = f2b(tile[tx][ty + i * 8]);  // coalesced store
    }
}

// ---------------- layer kernels ----------------

// first layer: [M,6] @ [6,512], scaled by dis, bf16 out; XCD-affine block map
__global__ void pre0_kernel(const float* __restrict__ x, const float* __restrict__ sdf,
                            const float* __restrict__ W, const float* __restrict__ dis,
                            short* __restrict__ B, int M) {
    int b = xcd_node_block(blockIdx.x);
    int m = b * 4 + (threadIdx.x >> 6);
    int n8 = (threadIdx.x & 63) << 3;
    if (m >= M) return;
    float a0 = x[m*5+0], a1 = x[m*5+1], a2 = x[m*5+2], a3 = x[m*5+3], a4 = x[m*5+4], a5 = sdf[m];
    float d = dis[m];
    s16x8 o;
#pragma unroll
    for (int j = 0; j < 8; ++j) {
        int n = n8 + j;
        float t = a0*W[n] + a1*W[512+n] + a2*W[1024+n] + a3*W[1536+n] + a4*W[2048+n] + a5*W[2560+n];
        o[j] = f2b(d * t);
    }
    *(s16x8*)&B[(size_t)m*512 + n8] = o;
}

// MFMA GEMM v5 (r10/r14 verbatim -- measured plateau 91-92 us, at reference
// parity for this shape): 128x128 tile, BK=32, 16 K-tiles, 3 LDS buffers,
// depth-2 counted-vmcnt, chunk-XOR swizzle both sides, XCD map rp%8.
__global__ __launch_bounds__(256) void gemm512_mfma_kernel(
        const short* __restrict__ A, const short* __restrict__ WT,
        const float* __restrict__ dis, short* __restrict__ C, int M,
        const float* __restrict__ A2, const float* __restrict__ W2) {
    __shared__ __attribute__((aligned(16))) short As[3][128 * 32];   // 3 x 8 KB
    __shared__ __attribute__((aligned(16))) short Bs[3][128 * 32];   // 3 x 8 KB
    int tid  = threadIdx.x;
    int lane = tid & 63;
    int w    = tid >> 6;          // 0..3
    int wr   = w >> 1, wc = w & 1;

    int nrp = (M + 127) >> 7;     // 391 row-panels
    int id = blockIdx.x;
    int rp = (id >> 5) * 8 + (id & 7);   // id&7 fixed per rp -> same XCD
    int cp = (id >> 3) & 3;              // col-panel 0..3
    if (rp >= nrp) return;
    int row0 = rp * 128;
    int col0 = cp * 128;

    const short* aRow[2];
    const short* bRow[2];
    int ldsOff[2];
#pragma unroll
    for (int g = 0; g < 2; ++g) {
        int r = w * 32 + g * 16 + (lane >> 2);
        int ar = row0 + r; if (ar >= M) ar = M - 1;
        int sch = (lane & 3) ^ ((r >> 1) & 3);      // pre-swizzled source chunk
        aRow[g] = A  + (size_t)ar * 512 + sch * 8;
        bRow[g] = WT + (size_t)(col0 + r) * 512 + sch * 8;
        ldsOff[g] = (w * 32 + g * 16) * 32;         // wave-uniform (shorts)
    }

    int ks = lane >> 4;           // k-slot 0..3 (8 shorts each)
    int aOff[4], bOff[4];
#pragma unroll
    for (int mi = 0; mi < 4; ++mi) {
        int r = wr * 64 + mi * 16 + (lane & 15);
        aOff[mi] = r * 32 + ((ks ^ ((r >> 1) & 3)) * 8);
    }
#pragma unroll
    for (int ni = 0; ni < 4; ++ni) {
        int c = wc * 64 + ni * 16 + (lane & 15);
        bOff[ni] = c * 32 + ((ks ^ ((c >> 1) & 3)) * 8);
    }

    f32x4 acc[4][4] = {};

    auto stage = [&](int buf, int k0) {   // 4 GL16/wave
#pragma unroll
        for (int g = 0; g < 2; ++g) {
            GL16(aRow[g] + k0, &As[buf][ldsOff[g]]);
            GL16(bRow[g] + k0, &Bs[buf][ldsOff[g]]);
        }
    };
    auto compute = [&](int buf) {
        s16x8 av[4], bv[4];
#pragma unroll
        for (int mi = 0; mi < 4; ++mi) av[mi] = *(const s16x8*)&As[buf][aOff[mi]];
#pragma unroll
        for (int ni = 0; ni < 4; ++ni) bv[ni] = *(const s16x8*)&Bs[buf][bOff[ni]];
#pragma unroll
        for (int mi = 0; mi < 4; ++mi)
#pragma unroll
            for (int ni = 0; ni < 4; ++ni)
                acc[mi][ni] = __builtin_amdgcn_mfma_f32_16x16x32_bf16(av[mi], bv[ni], acc[mi][ni], 0, 0, 0);
    };

    stage(0, 0);
    stage(1, 32);
    int buf = 0;
#pragma unroll 1
    for (int t = 0; t < 16; ++t) {
        if (t + 2 < 16) {
            int b2 = buf + 2; if (b2 >= 3) b2 -= 3;
            stage(b2, (t + 2) * 32);                           // keep 2 tiles in flight
            asm volatile("s_waitcnt vmcnt(8)" ::: "memory");   // tile t retired (in-order)
        } else if (t + 1 < 16) {
            asm volatile("s_waitcnt vmcnt(4)" ::: "memory");
        } else {
            asm volatile("s_waitcnt vmcnt(0)" ::: "memory");
        }
        __builtin_amdgcn_s_barrier();
        __builtin_amdgcn_sched_barrier(0);
        compute(buf);
        __builtin_amdgcn_sched_barrier(0);
        __builtin_amdgcn_s_barrier();
        __builtin_amdgcn_sched_barrier(0);
        ++buf; if (buf == 3) buf = 0;
    }

    int rbase = row0 + wr * 64;
    int cbase = col0 + wc * 64;
#pragma unroll
    for (int mi = 0; mi < 4; ++mi) {
#pragma unroll
        for (int r = 0; r < 4; ++r) {
            int row = rbase + mi * 16 + (lane >> 4) * 4 + r;
            if (row >= M) continue;
            float d = dis[row];
            float a20 = 0.f, a21 = 0.f, a22 = 0.f;
            if (A2) { a20 = A2[row*3+0]; a21 = A2[row*3+1]; a22 = A2[row*3+2]; }
#pragma unroll
            for (int ni = 0; ni < 4; ++ni) {
                int col = cbase + ni * 16 + (lane & 15);
                float v = acc[mi][ni][r];
                if (A2) v += a20 * W2[col] + a21 * W2[512 + col] + a22 * W2[1024 + col];
                C[(size_t)row * 512 + col] = f2b(d * v);
            }
        }
    }
}

// out[i,:] = bf16(relu( dis[i]*(sum_nbr B[src,:] + B[i,:]) + bias ))
// one wave/node; 8-deep index-prefetch gather windows + split accumulators
__global__ __launch_bounds__(256) void spmm512_kernel(
        const short* __restrict__ B, const int* __restrict__ rowptr, const int* __restrict__ esrc,
        const float* __restrict__ dis, const float* __restrict__ bias,
        short* __restrict__ out, int M) {
    int b = xcd_node_block(blockIdx.x);
    int node = b * 4 + (threadIdx.x >> 6);
    int lane = threadIdx.x & 63;
    if (node >= M) return;
    const s16x8* Bv = (const s16x8*)B;
    s16x8 v = Bv[(size_t)node * 64 + lane];   // self loop
    float accA[8], accB[8];
#pragma unroll
    for (int j = 0; j < 8; ++j) { accA[j] = b2f(v[j]); accB[j] = 0.f; }
    int s = rowptr[node], e = rowptr[node + 1];
    int p = s;
    // 8-deep window: prefetch indices, burst-issue 8 gathers, tree-accumulate
    for (; p + 8 <= e; p += 8) {
        int i0 = esrc[p+0], i1 = esrc[p+1], i2 = esrc[p+2], i3 = esrc[p+3];
        int i4 = esrc[p+4], i5 = esrc[p+5], i6 = esrc[p+6], i7 = esrc[p+7];
        s16x8 t0 = Bv[(size_t)i0 * 64 + lane];
        s16x8 t1 = Bv[(size_t)i1 * 64 + lane];
        s16x8 t2 = Bv[(size_t)i2 * 64 + lane];
        s16x8 t3 = Bv[(size_t)i3 * 64 + lane];
        s16x8 t4 = Bv[(size_t)i4 * 64 + lane];
        s16x8 t5 = Bv[(size_t)i5 * 64 + lane];
        s16x8 t6 = Bv[(size_t)i6 * 64 + lane];
        s16x8 t7 = Bv[(size_t)i7 * 64 + lane];
#pragma unroll
        for (int j = 0; j < 8; ++j) {
            accA[j] += (b2f(t0[j]) + b2f(t1[j])) + (b2f(t2[j]) + b2f(t3[j]));
            accB[j] += (b2f(t4[j]) + b2f(t5[j])) + (b2f(t6[j]) + b2f(t7[j]));
        }
    }
    for (; p + 4 <= e; p += 4) {
        int i0 = esrc[p+0], i1 = esrc[p+1], i2 = esrc[p+2], i3 = esrc[p+3];
        s16x8 t0 = Bv[(size_t)i0 * 64 + lane];
        s16x8 t1 = Bv[(size_t)i1 * 64 + lane];
        s16x8 t2 = Bv[(size_t)i2 * 64 + lane];
        s16x8 t3 = Bv[(size_t)i3 * 64 + lane];
#pragma unroll
        for (int j = 0; j < 8; ++j) {
            accA[j] += b2f(t0[j]) + b2f(t1[j]);
            accB[j] += b2f(t2[j]) + b2f(t3[j]);
        }
    }
    if (p + 2 <= e) {
        int i0 = esrc[p], i1 = esrc[p+1];
        s16x8 t0 = Bv[(size_t)i0 * 64 + lane];
        s16x8 t1 = Bv[(size_t)i1 * 64 + lane];
#pragma unroll
        for (int j = 0; j < 8; ++j) { accA[j] += b2f(t0[j]); accB[j] += b2f(t1[j]); }
        p += 2;
    }
    if (p < e) {
        int i0 = esrc[p];
        s16x8 t0 = Bv[(size_t)i0 * 64 + lane];
#pragma unroll
        for (int j = 0; j < 8; ++j) accA[j] += b2f(t0[j]);
    }
    float d = dis[node];
    const float4* bp = (const float4*)bias;
    float4 bb0 = bp[lane * 2], bb1 = bp[lane * 2 + 1];
    float r[8];
    r[0] = d*(accA[0]+accB[0]) + bb0.x; r[1] = d*(accA[1]+accB[1]) + bb0.y;
    r[2] = d*(accA[2]+accB[2]) + bb0.z; r[3] = d*(accA[3]+accB[3]) + bb0.w;
    r[4] = d*(accA[4]+accB[4]) + bb1.x; r[5] = d*(accA[5]+accB[5]) + bb1.y;
    r[6] = d*(accA[6]+accB[6]) + bb1.z; r[7] = d*(accA[7]+accB[7]) + bb1.w;
    s16x8 o;
#pragma unroll
    for (int j = 0; j < 8; ++j) o[j] = f2b(fmaxf(r[j], 0.f));
    ((s16x8*)out)[(size_t)node * 64 + lane] = o;
}

// final GEMM: B3[M,3] = dis .* (A_bf16[M,512] @ W[512,3]); one wave per row
__global__ __launch_bounds__(256) void gemm_n3_kernel(
        const short* __restrict__ A, const float* __restrict__ W,
        const float* __restrict__ dis, float* __restrict__ B3, int M) {
    int wid = (blockIdx.x * 256 + threadIdx.x) >> 6;
    int lane = threadIdx.x & 63;
    if (wid >= M) return;
    s16x8 v = ((const s16x8*)A)[(size_t)wid * 64 + lane];
    float s0 = 0.f, s1 = 0.f, s2 = 0.f;
#pragma unroll
    for (int j = 0; j < 8; ++j) {
        float a = b2f(v[j]);
        int k = lane * 8 + j;
        s0 += a * W[k*3+0];
        s1 += a * W[k*3+1];
        s2 += a * W[k*3+2];
    }
    for (int off = 32; off > 0; off >>= 1) {
        s0 += __shfl_down(s0, off);
        s1 += __shfl_down(s1, off);
        s2 += __shfl_down(s2, off);
    }
    if (lane == 0) {
        float d = dis[wid];
        B3[wid*3+0] = d * s0;
        B3[wid*3+1] = d * s1;
        B3[wid*3+2] = d * s2;
    }
}

__global__ void spmm3_kernel(const float* __restrict__ B3, const int* __restrict__ rowptr,
                             const int* __restrict__ esrc, const float* __restrict__ dis,
                             const float* __restrict__ bias, float* __restrict__ out, int M) {
    int i = blockIdx.x * 256 + threadIdx.x;
    if (i >= M) return;
    float a0 = B3[i*3+0], a1 = B3[i*3+1], a2 = B3[i*3+2];
    int s = rowptr[i], e = rowptr[i + 1];
    for (int p = s; p < e; ++p) {
        int src = esrc[p];
        a0 += B3[src*3+0];
        a1 += B3[src*3+1];
        a2 += B3[src*3+2];
    }
    float d = dis[i];
    out[i*3+0] = d * a0 + bias[0];
    out[i*3+1] = d * a1 + bias[1];
    out[i*3+2] = d * a2 + bias[2];
}

// KNN interpolate: block = 64 fine nodes x 4 waves; wave w scans coarse chunk of 500.
__global__ __launch_bounds__(256) void knn_kernel(
        const float* __restrict__ x, const float* __restrict__ cpos,
        const float* __restrict__ cy, float* __restrict__ fy, int M) {
    __shared__ float sd[12][64];
    __shared__ int   si[12][64];
    int lane = threadIdx.x & 63;
    int w = threadIdx.x >> 6;
    int gi = blockIdx.x * 64 + lane;
    int i = (gi < M) ? gi : (M - 1);
    float px = x[i*5+0], py = x[i*5+1];
    float pn2 = px*px + py*py;
    float d0 = 3.0e38f, d1 = 3.0e38f, d2 = 3.0e38f;
    int i0 = 0x7fffffff, i1 = 0x7fffffff, i2 = 0x7fffffff;
    int c0 = w * (N_COARSE / 4), c1 = c0 + (N_COARSE / 4);
    for (int c = c0; c < c1; ++c) {
        float a = cpos[c*2+0], b = cpos[c*2+1];
        float sn2 = a*a + b*b;                       // ref formula
        float d = pn2 + sn2 - 2.f * (px * a + py * b);
        if (d < d2) {
            if (d < d1) {
                d2 = d1; i2 = i1;
                if (d < d0) { d1 = d0; i1 = i0; d0 = d; i0 = c; }
                else       { d1 = d;  i1 = c; }
            } else { d2 = d; i2 = c; }
        }
    }
    sd[w*3+0][lane] = d0; si[w*3+0][lane] = i0;
    sd[w*3+1][lane] = d1; si[w*3+1][lane] = i1;
    sd[w*3+2][lane] = d2; si[w*3+2][lane] = i2;
    __syncthreads();
    if (w != 0 || gi >= M) return;
    float cd[12]; int ci[12];
#pragma unroll
    for (int q = 0; q < 12; ++q) { cd[q] = sd[q][lane]; ci[q] = si[q][lane]; }
    float bd[3]; int bi[3];
#pragma unroll
    for (int s = 0; s < 3; ++s) {
        float best = 3.4e38f; int besti = 0x7fffffff; int bq = 0;
#pragma unroll
        for (int q = 0; q < 12; ++q) {
            bool better = (cd[q] < best) || (cd[q] == best && ci[q] < besti);
            if (better) { best = cd[q]; besti = ci[q]; bq = q; }
        }
        bd[s] = best; bi[s] = besti;
        cd[bq] = 3.4e38f; ci[bq] = 0x7fffffff;
    }
    float w0 = 1.f / fmaxf(bd[0], 1e-16f);
    float w1 = 1.f / fmaxf(bd[1], 1e-16f);
    float w2 = 1.f / fmaxf(bd[2], 1e-16f);
    float ws = w0 + w1 + w2;
    int j0 = bi[0], j1 = bi[1], j2 = bi[2];
#pragma unroll
    for (int j = 0; j < 3; ++j) {
        float v = w0 * cy[j0*3+j] + w1 * cy[j1*3+j] + w2 * cy[j2*3+j];
        fy[gi*3+j] = v / ws;
    }
}

// ---------------- launch ----------------

extern "C" void kernel_launch(void* const* d_in, const int* in_sizes, int n_in,
                              void* d_out, int out_size, void* d_ws, size_t ws_size,
                              hipStream_t stream) {
    const float* x        = (const float*)d_in[0];
    const float* sdf      = (const float*)d_in[1];
    const float* coarse_x = (const float*)d_in[2];
    const float* coarse_y = (const float*)d_in[3];
    const int*   eidx     = (const int*)d_in[4];
    const float* pre_W0   = (const float*)d_in[5];
    const float* pre_b0   = (const float*)d_in[6];
    const float* pre_W1   = (const float*)d_in[7];
    const float* pre_b1   = (const float*)d_in[8];
    const float* pre_W2   = (const float*)d_in[9];
    const float* pre_b2   = (const float*)d_in[10];
    const float* end_W0   = (const float*)d_in[11];
    const float* end_b0   = (const float*)d_in[12];
    const float* end_W1   = (const float*)d_in[13];
    const float* end_b1   = (const float*)d_in[14];
    const float* end_W2   = (const float*)d_in[15];
    const float* end_b2   = (const float*)d_in[16];
    float* out = (float*)d_out;

    const int M = N_FINE, NE = N_EDGES;
    const int* erow = eidx;
    const int* ecol = eidx + NE;

    char* base = (char*)d_ws;
    size_t off = 0;
    auto alloc = [&](size_t bytes) { char* p = base + off; off = (off + bytes + 255) & ~(size_t)255; return p; };
    int*   counts = (int*)  alloc((size_t)M * 4);
    int*   rowptr = (int*)  alloc((size_t)(M + 1) * 4);
    int*   cursor = (int*)  alloc((size_t)M * 4);
    int*   esrc   = (int*)  alloc((size_t)NE * 4);
    int*   blksum = (int*)  alloc((size_t)64 * 4);
    float* dis    = (float*)alloc((size_t)M * 4);
    float* fy     = (float*)alloc((size_t)M * 3 * 4);
    float* B3     = (float*)alloc((size_t)M * 3 * 4);
    short* WT1    = (short*)alloc((size_t)512 * 512 * 2);
    short* WT2    = (short*)alloc((size_t)512 * 512 * 2);
    short* WT3    = (short*)alloc((size_t)512 * 512 * 2);
    short* WT4    = (short*)alloc((size_t)512 * 512 * 2);
    short* bufA   = (short*)alloc((size_t)M * 512 * 2);
    short* bufB   = (short*)alloc((size_t)M * 512 * 2);
    (void)ws_size;

    // weight prep (one launch, 4 matrices)
    wt4_kernel<<<dim3(256, 4), 256, 0, stream>>>(pre_W1, pre_W2, end_W0 + 3 * 512, end_W1,
                                                 WT1, WT2, WT3, WT4);

    // CSR + degrees (compressed chain: dis fused into scan, cursor fused into add)
    hipMemsetAsync(counts, 0, (size_t)M * 4, stream);
    count_edges_kernel<<<cdiv(NE, 256), 256, 0, stream>>>(ecol, counts, NE);
    int nb = cdiv(M, 1024);
    scan_block_kernel<<<nb, 1024, 0, stream>>>(counts, rowptr, blksum, dis, M);
    scan_tops_kernel<<<1, 64, 0, stream>>>(blksum, nb);
    scan_add_kernel<<<cdiv(M + 1, 256), 256, 0, stream>>>(rowptr, cursor, blksum, M);
    scatter_edges_kernel<<<cdiv(NE, 256), 256, 0, stream>>>(erow, ecol, cursor, esrc, NE);

    // KNN interpolate
    knn_kernel<<<cdiv(M, 64), 256, 0, stream>>>(x, coarse_x, coarse_y, fy, M);

    // gemm grid: 391 row-panels x 4 col-panels; id = (rp>>3)*32 + cp*8 + (rp&7)
    int nrp = cdiv(M, 128);
    int ggrid = cdiv(nrp, 8) * 32;
    // node-parallel grid (pre0/spmm): XCD-affine remap over 128-node panels
    int sgrid = cdiv(cdiv(M, 128), 8) * 256;   // 12544

    pre0_kernel<<<sgrid, 256, 0, stream>>>(x, sdf, pre_W0, dis, bufB, M);
    spmm512_kernel<<<sgrid, 256, 0, stream>>>(bufB, rowptr, esrc, dis, pre_b0, bufA, M);

    gemm512_mfma_kernel<<<ggrid, 256, 0, stream>>>(bufA, WT1, dis, bufB, M, nullptr, nullptr);
    spmm512_kernel<<<sgrid, 256, 0, stream>>>(bufB, rowptr, esrc, dis, pre_b1, bufA, M);

    gemm512_mfma_kernel<<<ggrid, 256, 0, stream>>>(bufA, WT2, dis, bufB, M, nullptr, nullptr);
    spmm512_kernel<<<sgrid, 256, 0, stream>>>(bufB, rowptr, esrc, dis, pre_b2, bufA, M);

    gemm512_mfma_kernel<<<ggrid, 256, 0, stream>>>(bufA, WT3, dis, bufB, M, fy, end_W0);
    spmm512_kernel<<<sgrid, 256, 0, stream>>>(bufB, rowptr, esrc, dis, end_b0, bufA, M);

    gemm512_mfma_kernel<<<ggrid, 256, 0, stream>>>(bufA, WT4, dis, bufB, M, nullptr, nullptr);
    spmm512_kernel<<<sgrid, 256, 0, stream>>>(bufB, rowptr, esrc, dis, end_b1, bufA, M);

    gemm_n3_kernel<<<cdiv(M * 64, 256), 256, 0, stream>>>(bufA, end_W2, dis, B3, M);
    spmm3_kernel<<<cdiv(M, 256), 256, 0, stream>>>(B3, rowptr, esrc, dis, end_b2, out, M);
}